// Round 5
// baseline (1460.458 us; speedup 1.0000x reference)
//
#include <hip/hip_runtime.h>

#define DI static __device__ __forceinline__

typedef float v2f __attribute__((ext_vector_type(2)));

DI unsigned short f2bf(float f) {
  unsigned int u = __float_as_uint(f);
  u = (u + 0x7fffu + ((u >> 16) & 1u)) >> 16;
  return (unsigned short)u;
}
DI float bf2f(unsigned short h) { return __uint_as_float(((unsigned int)h) << 16); }

// ---------------------------------------------------------------------------
// Mega-kernel: blocks 0..15 run FPS (serial, latency-bound, 16 CUs); blocks
// 16..1039 run the p0 GEMM (P0 = W0[:,3:]*points) on the otherwise-idle CUs.
//
// FPS distance arithmetic is the exact rn sequence verified bit-exact in r3:
//   d = ((dx*dx + dy*dy) + dz*dz), elementwise rn, NO contraction
//   (fp contract(off) pragma; v2f ops are elementwise rn = same bits).
// Argmax: pack (dist_bits<<32)|~idx u64, 6-level shfl_xor butterfly,
// per-wave winner writes key AND centroid coords to parity slot -> after the
// single barrier, threads do 4-way key max + coord select (no XL round-trip).
// ---------------------------------------------------------------------------
__global__ __launch_bounds__(256) void fps_p0_kernel(
    const float* __restrict__ xyz, float* __restrict__ newxyz,
    const float* __restrict__ points, const float* __restrict__ w0,
    float* __restrict__ P0) {
  __shared__ union {
    struct {
      float XL[4096 * 3];
      unsigned long long skey[2][4];
      float scd[2][4][3];
    } f;
    float W[64][64];
  } su;
  const int t = threadIdx.x;

  if (blockIdx.x >= 16) {
    // ---------------- p0 GEMM branch ----------------
    const int bid = blockIdx.x - 16;
    const int b = bid >> 6;
    const int n0 = (bid & 63) << 6;
    for (int idx = t; idx < 4096; idx += 256) {
      int c = idx >> 6, o = idx & 63;
      su.W[c][o] = w0[o * 67 + 3 + c];
    }
    __syncthreads();
    const int i = t >> 4, j = t & 15;
    const float* Pb = points + (size_t)b * 64 * 4096 + n0 + 4 * i;
    float acc[4][4] = {};
    for (int c = 0; c < 64; ++c) {
      float4 xv = *(const float4*)(Pb + (size_t)c * 4096);
      float4 wv = *(const float4*)&su.W[c][4 * j];
      float xr[4] = {xv.x, xv.y, xv.z, xv.w};
      float wr[4] = {wv.x, wv.y, wv.z, wv.w};
#pragma unroll
      for (int rr = 0; rr < 4; ++rr)
#pragma unroll
        for (int oi = 0; oi < 4; ++oi) acc[rr][oi] = fmaf(xr[rr], wr[oi], acc[rr][oi]);
    }
#pragma unroll
    for (int rr = 0; rr < 4; ++rr) {
      float4 vv = make_float4(acc[rr][0], acc[rr][1], acc[rr][2], acc[rr][3]);
      *(float4*)(P0 + ((size_t)b * 4096 + n0 + 4 * i + rr) * 64 + 4 * j) = vv;
    }
    return;
  }

  // ---------------- FPS branch ----------------
  const int b = blockIdx.x;
  const int lane = t & 63, wid = t >> 6;
  const float* X = xyz + (size_t)b * 4096 * 3;
  for (int idx = t; idx < 12288; idx += 256) su.f.XL[idx] = X[idx];
  v2f px[8], py[8], pz[8], dist[8];
#pragma unroll
  for (int q = 0; q < 8; ++q) {
    int i0 = t + (q << 9);   // point 2q*256 + t
    int i1 = i0 + 256;       // point (2q+1)*256 + t
    px[q] = (v2f){X[i0 * 3 + 0], X[i1 * 3 + 0]};
    py[q] = (v2f){X[i0 * 3 + 1], X[i1 * 3 + 1]};
    pz[q] = (v2f){X[i0 * 3 + 2], X[i1 * 3 + 2]};
    dist[q] = (v2f){3.402823466e38f, 3.402823466e38f};
  }
  __syncthreads();
  float cx = su.f.XL[0], cy = su.f.XL[1], cz = su.f.XL[2];  // farthest = 0
  const unsigned int nt = ~(unsigned int)t;
  float* out = newxyz + (size_t)b * 1024 * 3;
  for (int s = 0; s < 1024; ++s) {
    if (t == 0) { out[s * 3 + 0] = cx; out[s * 3 + 1] = cy; out[s * 3 + 2] = cz; }
    float bv = -1.0f;
    unsigned int bl = 0;
    v2f cxv = (v2f){cx, cx}, cyv = (v2f){cy, cy}, czv = (v2f){cz, cz};
#pragma unroll
    for (int q = 0; q < 8; ++q) {
#pragma clang fp contract(off)
      v2f dx = px[q] - cxv;
      v2f dy = py[q] - cyv;
      v2f dz = pz[q] - czv;
      v2f d = (dx * dx + dy * dy) + dz * dz;  // elementwise rn, contraction off
#if __has_builtin(__builtin_elementwise_min)
      v2f nd = __builtin_elementwise_min(dist[q], d);
#else
      v2f nd;
      nd.x = fminf(dist[q].x, d.x);
      nd.y = fminf(dist[q].y, d.y);
#endif
      dist[q] = nd;
      float n0 = nd.x, n1 = nd.y;
      bool c0 = (n0 > bv);  // strict >: earlier (smaller) index kept on ties
      bv = c0 ? n0 : bv;
      bl = c0 ? (nt - (unsigned int)(q << 9)) : bl;          // ~(t + 2q*256)
      bool c1 = (n1 > bv);
      bv = c1 ? n1 : bv;
      bl = c1 ? (nt - (unsigned int)((q << 9) + 256)) : bl;  // ~(t + (2q+1)*256)
    }
    unsigned long long best =
        ((unsigned long long)__float_as_uint(bv) << 32) | (unsigned long long)bl;
#pragma unroll
    for (int m = 1; m < 64; m <<= 1) {
      unsigned long long o = __shfl_xor(best, m, 64);
      best = (o > best) ? o : best;
    }
    const int p = s & 1;
    if (lane == 0) {
      int fi = (int)(~(unsigned int)best);  // winner index in [0,4095]
      su.f.skey[p][wid] = best;
      su.f.scd[p][wid][0] = su.f.XL[fi * 3 + 0];
      su.f.scd[p][wid][1] = su.f.XL[fi * 3 + 1];
      su.f.scd[p][wid][2] = su.f.XL[fi * 3 + 2];
    }
    __syncthreads();
    unsigned long long k0 = su.f.skey[p][0], k1 = su.f.skey[p][1];
    unsigned long long k2 = su.f.skey[p][2], k3 = su.f.skey[p][3];
    bool c01 = (k0 >= k1);  // keys distinct (unique index bits)
    unsigned long long m01 = c01 ? k0 : k1;
    float x01 = c01 ? su.f.scd[p][0][0] : su.f.scd[p][1][0];
    float y01 = c01 ? su.f.scd[p][0][1] : su.f.scd[p][1][1];
    float z01 = c01 ? su.f.scd[p][0][2] : su.f.scd[p][1][2];
    bool c23 = (k2 >= k3);
    unsigned long long m23 = c23 ? k2 : k3;
    float x23 = c23 ? su.f.scd[p][2][0] : su.f.scd[p][3][0];
    float y23 = c23 ? su.f.scd[p][2][1] : su.f.scd[p][3][1];
    float z23 = c23 ? su.f.scd[p][2][2] : su.f.scd[p][3][2];
    bool cw = (m01 >= m23);
    cx = cw ? x01 : x23;
    cy = cw ? y01 : y23;
    cz = cw ? z01 : z23;
  }
}

// ---------------------------------------------------------------------------
// Ball query fused with layer-0 stats accumulation.
// sqr emulates XLA-CPU fp32 arithmetic of the reference (VERIFIED r3):
//   dot  = fma chain over d; cs/xs = plain rn; sqr = rn((cs+xs) - 2*dot)
// One wave per group, 4 groups per block, grid = 4096.
// ---------------------------------------------------------------------------
__global__ __launch_bounds__(256) void ballquery_stats0_kernel(
    const float* __restrict__ xyz, const float* __restrict__ newxyz,
    const float* __restrict__ P0, const float* __restrict__ w0,
    int* __restrict__ gidx, float* __restrict__ partials0) {
  const int t = threadIdx.x;
  const int lane = t & 63, w = t >> 6;
  const int gid = blockIdx.x * 4 + w;  // 0..16383
  const int b = gid >> 10;
  __shared__ int sel[4][32];
  __shared__ float red[4][128];
  const float* Xb = xyz + (size_t)b * 4096 * 3;
  const float cx = newxyz[(size_t)gid * 3 + 0];
  const float cy = newxyz[(size_t)gid * 3 + 1];
  const float cz = newxyz[(size_t)gid * 3 + 2];
  const float cs = __fadd_rn(__fadd_rn(__fmul_rn(cx, cx), __fmul_rn(cy, cy)), __fmul_rn(cz, cz));
  int cnt = 0, first = 0;
  bool found = false;
  for (int base = 0; base < 4096; base += 64) {
    int i = base + lane;
    float x = Xb[i * 3 + 0], y = Xb[i * 3 + 1], z = Xb[i * 3 + 2];
    float xs = __fadd_rn(__fadd_rn(__fmul_rn(x, x), __fmul_rn(y, y)), __fmul_rn(z, z));
    float dot = fmaf(cz, z, fmaf(cy, y, __fmul_rn(cx, x)));  // fma chain, d=0,1,2
    float sqr = __fsub_rn(__fadd_rn(cs, xs), __fmul_rn(2.0f, dot));
    bool ok = sqr <= 0.04f;
    unsigned long long mask = __ballot(ok);
    if (!found && mask != 0ull) { first = base + __builtin_ctzll(mask); found = true; }
    int pre = __popcll(mask & ((1ull << lane) - 1ull));
    int pos = cnt + pre;
    if (ok && pos < 32) sel[w][pos] = i;
    cnt += (int)__popcll(mask);
    if (cnt >= 32) break;
  }
  if (cnt < 32) {
    int pad = found ? first : 0;
    for (int p = cnt + lane; p < 32; p += 64) sel[w][p] = pad;
  }
  __syncthreads();
  if (lane < 32) gidx[(size_t)gid * 32 + lane] = sel[w][lane];
  // ---- stats for act0 (pre-BN layer0 output): lane = channel c ----
  const int c = lane;
  float wx = w0[c * 67 + 0], wy = w0[c * 67 + 1], wz = w0[c * 67 + 2];
  float ssum = 0.f, ssq = 0.f;
  const float* P0b = P0 + (size_t)b * 4096 * 64;
  for (int k = 0; k < 32; ++k) {
    int g = sel[w][k];
    float gx = Xb[g * 3 + 0] - cx, gy = Xb[g * 3 + 1] - cy, gz = Xb[g * 3 + 2] - cz;
    float a0 = fmaf(wx, gx, fmaf(wy, gy, fmaf(wz, gz, P0b[(size_t)g * 64 + c])));
    ssum += a0;
    ssq = fmaf(a0, a0, ssq);
  }
  red[w][c] = ssum;
  red[w][c + 64] = ssq;
  __syncthreads();
  if (t < 128) {
    float acc = red[0][t] + red[1][t] + red[2][t] + red[3][t];
    partials0[(size_t)t * 4096 + blockIdx.x] = acc;
  }
}

// ---------------------------------------------------------------------------
// finalize BN stats: scale = g*rsqrt(var+eps), shift = b - mean*scale
// ---------------------------------------------------------------------------
__global__ __launch_bounds__(256) void finalize_kernel(
    const float* __restrict__ partials, int C, int nblk,
    const float* __restrict__ gamma, const float* __restrict__ beta,
    float* __restrict__ scale, float* __restrict__ shift) {
  const int c = blockIdx.x, t = threadIdx.x;
  double s1 = 0.0, s2 = 0.0;
  for (int k = t; k < nblk; k += 256) {
    s1 += (double)partials[(size_t)c * nblk + k];
    s2 += (double)partials[(size_t)(C + c) * nblk + k];
  }
  __shared__ double r1[256], r2[256];
  r1[t] = s1;
  r2[t] = s2;
  __syncthreads();
  for (int off = 128; off > 0; off >>= 1) {
    if (t < off) { r1[t] += r1[t + off]; r2[t] += r2[t + off]; }
    __syncthreads();
  }
  if (t == 0) {
    const double M = 524288.0;
    double mean = r1[0] / M;
    double var = r2[0] / M - mean * mean;
    if (var < 0.0) var = 0.0;
    float sc = gamma[c] * (float)(1.0 / sqrt(var + 1e-5));
    scale[c] = sc;
    shift[c] = beta[c] - (float)mean * sc;
  }
}

// ---------------------------------------------------------------------------
// P2: act1_raw = W1 * relu(bn0(act0)), store bf16, accumulate stats1.
// grid = 1024 blocks x 8 tiles x 64 rows. 256 thr: 4-row x 4-out register tile.
// ---------------------------------------------------------------------------
__global__ __launch_bounds__(256) void p2_kernel(
    const float* __restrict__ xyz, const float* __restrict__ newxyz,
    const float* __restrict__ P0, const int* __restrict__ gidx,
    const float* __restrict__ w0, const float* __restrict__ w1,
    const float* __restrict__ sc0g, const float* __restrict__ sh0g,
    unsigned short* __restrict__ act1, float* __restrict__ partials1) {
  __shared__ float W1s[64][64];  // [c][o]
  __shared__ float Xs[64][64];   // [c][row]
  __shared__ float w0x[64], w0y[64], w0z[64], sc0[64], sh0[64];
  __shared__ float Sred[256][8];
  const int t = threadIdx.x;
  for (int idx = t; idx < 4096; idx += 256) {
    int c = idx >> 6, o = idx & 63;
    W1s[c][o] = w1[o * 64 + c];
  }
  if (t < 64) {
    w0x[t] = w0[t * 67 + 0];
    w0y[t] = w0[t * 67 + 1];
    w0z[t] = w0[t * 67 + 2];
    sc0[t] = sc0g[t];
    sh0[t] = sh0g[t];
  }
  __syncthreads();
  const int i = t >> 4, j = t & 15;
  const int rl = t >> 2, cq = t & 3;
  float ssum[4] = {}, ssq[4] = {};
  for (int tile = 0; tile < 8; ++tile) {
    const int rowbase = (blockIdx.x * 8 + tile) << 6;
    {
      int r = rowbase + rl;
      int b = r >> 15, s = (r >> 5) & 1023;
      int g = gidx[r];
      const float* Pt = xyz + ((size_t)b * 4096 + g) * 3;
      const float* Ct = newxyz + ((size_t)b * 1024 + s) * 3;
      float dx = Pt[0] - Ct[0], dy = Pt[1] - Ct[1], dz = Pt[2] - Ct[2];
      const float* p0r = P0 + ((size_t)b * 4096 + g) * 64 + cq * 16;
      const float4* p4 = (const float4*)p0r;
      float4 a0 = p4[0], a1 = p4[1], a2 = p4[2], a3 = p4[3];
      float pv[16] = {a0.x, a0.y, a0.z, a0.w, a1.x, a1.y, a1.z, a1.w,
                      a2.x, a2.y, a2.z, a2.w, a3.x, a3.y, a3.z, a3.w};
#pragma unroll
      for (int cc = 0; cc < 16; ++cc) {
        int c = cq * 16 + cc;
        float a = fmaf(w0x[c], dx, fmaf(w0y[c], dy, fmaf(w0z[c], dz, pv[cc])));
        Xs[c][rl] = fmaxf(0.f, fmaf(a, sc0[c], sh0[c]));
      }
    }
    __syncthreads();
    float acc[4][4] = {};
#pragma unroll 4
    for (int c = 0; c < 64; ++c) {
      float4 xv = *(const float4*)&Xs[c][4 * i];
      float4 wv = *(const float4*)&W1s[c][4 * j];
      float xr[4] = {xv.x, xv.y, xv.z, xv.w};
      float wr[4] = {wv.x, wv.y, wv.z, wv.w};
#pragma unroll
      for (int rr = 0; rr < 4; ++rr)
#pragma unroll
        for (int oi = 0; oi < 4; ++oi) acc[rr][oi] = fmaf(xr[rr], wr[oi], acc[rr][oi]);
    }
#pragma unroll
    for (int rr = 0; rr < 4; ++rr) {
      size_t r = (size_t)rowbase + 4 * i + rr;
      ushort4 pk;
      float y0 = acc[rr][0], y1 = acc[rr][1], y2 = acc[rr][2], y3 = acc[rr][3];
      ssum[0] += y0; ssq[0] = fmaf(y0, y0, ssq[0]);
      ssum[1] += y1; ssq[1] = fmaf(y1, y1, ssq[1]);
      ssum[2] += y2; ssq[2] = fmaf(y2, y2, ssq[2]);
      ssum[3] += y3; ssq[3] = fmaf(y3, y3, ssq[3]);
      pk.x = f2bf(y0); pk.y = f2bf(y1); pk.z = f2bf(y2); pk.w = f2bf(y3);
      *(ushort4*)(act1 + r * 64 + 4 * j) = pk;
    }
    __syncthreads();
  }
#pragma unroll
  for (int oi = 0; oi < 4; ++oi) { Sred[t][oi] = ssum[oi]; Sred[t][4 + oi] = ssq[oi]; }
  __syncthreads();
  if (t < 64) {
    int jj = t >> 2, oi = t & 3;
    float s1 = 0.f, s2 = 0.f;
#pragma unroll
    for (int ii = 0; ii < 16; ++ii) {
      s1 += Sred[ii * 16 + jj][oi];
      s2 += Sred[ii * 16 + jj][4 + oi];
    }
    partials1[(size_t)t * 1024 + blockIdx.x] = s1;
    partials1[(size_t)(64 + t) * 1024 + blockIdx.x] = s2;
  }
}

// ---------------------------------------------------------------------------
// P3: stats of act2_raw = W2 * relu(bn1(act1)) (no store; P4 recomputes).
// ---------------------------------------------------------------------------
__global__ __launch_bounds__(256) void p3_kernel(
    const unsigned short* __restrict__ act1, const float* __restrict__ w2,
    const float* __restrict__ sc1g, const float* __restrict__ sh1g,
    float* __restrict__ partials2) {
  __shared__ float W2s[64][128];  // [c][o]
  __shared__ union US { float Xs[64][64]; float Sred[256][16]; } u;
  __shared__ float sc1[64], sh1[64];
  const int t = threadIdx.x;
  for (int idx = t; idx < 8192; idx += 256) {
    int c = idx >> 7, o = idx & 127;
    W2s[c][o] = w2[o * 64 + c];
  }
  if (t < 64) { sc1[t] = sc1g[t]; sh1[t] = sh1g[t]; }
  __syncthreads();
  const int i = t >> 4, j = t & 15;
  const int rl = t >> 2, cq = t & 3;
  float ssum[8] = {}, ssq[8] = {};
  for (int tile = 0; tile < 8; ++tile) {
    const int rowbase = (blockIdx.x * 8 + tile) << 6;
    {
      size_t r = (size_t)rowbase + rl;
      const uint4* pr = (const uint4*)(act1 + r * 64 + cq * 16);
      uint4 aa = pr[0], bb = pr[1];
      unsigned int uu[8] = {aa.x, aa.y, aa.z, aa.w, bb.x, bb.y, bb.z, bb.w};
#pragma unroll
      for (int q = 0; q < 8; ++q) {
        int c = cq * 16 + 2 * q;
        float v0 = bf2f((unsigned short)(uu[q] & 0xffffu));
        float v1 = bf2f((unsigned short)(uu[q] >> 16));
        u.Xs[c][rl] = fmaxf(0.f, fmaf(v0, sc1[c], sh1[c]));
        u.Xs[c + 1][rl] = fmaxf(0.f, fmaf(v1, sc1[c + 1], sh1[c + 1]));
      }
    }
    __syncthreads();
    float acc[4][8] = {};
#pragma unroll 2
    for (int c = 0; c < 64; ++c) {
      float4 xv = *(const float4*)&u.Xs[c][4 * i];
      float4 wa = *(const float4*)&W2s[c][4 * j];
      float4 wb = *(const float4*)&W2s[c][64 + 4 * j];
      float xr[4] = {xv.x, xv.y, xv.z, xv.w};
      float wr[8] = {wa.x, wa.y, wa.z, wa.w, wb.x, wb.y, wb.z, wb.w};
#pragma unroll
      for (int rr = 0; rr < 4; ++rr)
#pragma unroll
        for (int q = 0; q < 8; ++q) acc[rr][q] = fmaf(xr[rr], wr[q], acc[rr][q]);
    }
#pragma unroll
    for (int rr = 0; rr < 4; ++rr)
#pragma unroll
      for (int q = 0; q < 8; ++q) {
        float y = acc[rr][q];
        ssum[q] += y;
        ssq[q] = fmaf(y, y, ssq[q]);
      }
    __syncthreads();
  }
#pragma unroll
  for (int q = 0; q < 8; ++q) { u.Sred[t][q] = ssum[q]; u.Sred[t][8 + q] = ssq[q]; }
  __syncthreads();
  if (t < 128) {
    int o = t;
    int jj = (o & 63) >> 2, oh = o >> 6, oi = o & 3, slot = oh * 4 + oi;
    float s1 = 0.f, s2 = 0.f;
#pragma unroll
    for (int ii = 0; ii < 16; ++ii) {
      s1 += u.Sred[ii * 16 + jj][slot];
      s2 += u.Sred[ii * 16 + jj][8 + slot];
    }
    partials2[(size_t)o * 1024 + blockIdx.x] = s1;
    partials2[(size_t)(128 + o) * 1024 + blockIdx.x] = s2;
  }
}

// ---------------------------------------------------------------------------
// P4: recompute act2, bn2+relu, max over K=32, write feats[b][o][s].
// grid = 8192 blocks, 1 tile = 64 rows = 2 groups each.
// ---------------------------------------------------------------------------
__global__ __launch_bounds__(256) void p4_kernel(
    const unsigned short* __restrict__ act1, const float* __restrict__ w2,
    const float* __restrict__ sc1g, const float* __restrict__ sh1g,
    const float* __restrict__ sc2g, const float* __restrict__ sh2g,
    float* __restrict__ feats) {
  __shared__ float W2s[64][128];
  __shared__ float Xs[64][64];
  __shared__ float Mred[16][132];  // padded stride vs 128 to dodge bank conflicts
  __shared__ float sc1[64], sh1[64], sc2[128], sh2[128];
  const int t = threadIdx.x;
  for (int idx = t; idx < 8192; idx += 256) {
    int c = idx >> 7, o = idx & 127;
    W2s[c][o] = w2[o * 64 + c];
  }
  if (t < 64) { sc1[t] = sc1g[t]; sh1[t] = sh1g[t]; }
  if (t < 128) { sc2[t] = sc2g[t]; sh2[t] = sh2g[t]; }
  __syncthreads();
  const int i = t >> 4, j = t & 15;
  const int rl = t >> 2, cq = t & 3;
  const int rowbase = blockIdx.x << 6;
  {
    size_t r = (size_t)rowbase + rl;
    const uint4* pr = (const uint4*)(act1 + r * 64 + cq * 16);
    uint4 aa = pr[0], bb = pr[1];
    unsigned int uu[8] = {aa.x, aa.y, aa.z, aa.w, bb.x, bb.y, bb.z, bb.w};
#pragma unroll
    for (int q = 0; q < 8; ++q) {
      int c = cq * 16 + 2 * q;
      float v0 = bf2f((unsigned short)(uu[q] & 0xffffu));
      float v1 = bf2f((unsigned short)(uu[q] >> 16));
      Xs[c][rl] = fmaxf(0.f, fmaf(v0, sc1[c], sh1[c]));
      Xs[c + 1][rl] = fmaxf(0.f, fmaf(v1, sc1[c + 1], sh1[c + 1]));
    }
  }
  __syncthreads();
  float acc[4][8] = {};
#pragma unroll 2
  for (int c = 0; c < 64; ++c) {
    float4 xv = *(const float4*)&Xs[c][4 * i];
    float4 wa = *(const float4*)&W2s[c][4 * j];
    float4 wb = *(const float4*)&W2s[c][64 + 4 * j];
    float xr[4] = {xv.x, xv.y, xv.z, xv.w};
    float wr[8] = {wa.x, wa.y, wa.z, wa.w, wb.x, wb.y, wb.z, wb.w};
#pragma unroll
    for (int rr = 0; rr < 4; ++rr)
#pragma unroll
      for (int q = 0; q < 8; ++q) acc[rr][q] = fmaf(xr[rr], wr[q], acc[rr][q]);
  }
  // rows 4i..4i+3 are all in group (i>>3); per-thread max over them.
#pragma unroll
  for (int q = 0; q < 8; ++q) {
    int oh = q >> 2, oi = q & 3;
    int o = 4 * j + 64 * oh + oi;
    float m = 0.f;  // relu output >= 0
#pragma unroll
    for (int rr = 0; rr < 4; ++rr) {
      float v = fmaxf(0.f, fmaf(acc[rr][q], sc2[o], sh2[o]));
      m = fmaxf(m, v);
    }
    Mred[i][o] = m;
  }
  __syncthreads();
  {
    int o = t & 127, g = t >> 7;
    float v = 0.f;
#pragma unroll
    for (int ii = 0; ii < 8; ++ii) v = fmaxf(v, Mred[g * 8 + ii][o]);
    int b = rowbase >> 15;
    int s = ((rowbase >> 5) & 1023) + g;
    feats[(size_t)b * 131072 + (size_t)o * 1024 + s] = v;
  }
}

// ---------------------------------------------------------------------------
extern "C" void kernel_launch(void* const* d_in, const int* in_sizes, int n_in,
                              void* d_out, int out_size, void* d_ws, size_t ws_size,
                              hipStream_t stream) {
  const float* xyz = (const float*)d_in[0];
  const float* points = (const float*)d_in[1];
  const float* w0 = (const float*)d_in[2];
  const float* g0 = (const float*)d_in[3];
  const float* b0 = (const float*)d_in[4];
  const float* w1 = (const float*)d_in[5];
  const float* g1 = (const float*)d_in[6];
  const float* b1 = (const float*)d_in[7];
  const float* w2 = (const float*)d_in[8];
  const float* g2 = (const float*)d_in[9];
  const float* b2 = (const float*)d_in[10];

  float* out = (float*)d_out;
  float* newxyz = out;            // (16,1024,3)
  float* feats = out + 49152;     // (16,128,1024)

  char* ws = (char*)d_ws;
  float* P0 = (float*)ws;                                        // 16 MB  [b][n][64]
  int* gidx = (int*)(ws + (size_t)(16u << 20));                  // 2 MB
  unsigned short* act1 = (unsigned short*)(ws + (size_t)(18u << 20));  // 64 MB bf16
  float* partials0 = (float*)(ws + (size_t)(82u << 20));         // 2 MB   [128][4096]
  float* partials1 = (float*)(ws + (size_t)(84u << 20));         // 0.5 MB [128][1024]
  float* partials2 = (float*)(ws + (size_t)(85u << 20));         // 1 MB   [256][1024]
  float* sc0 = (float*)(ws + (size_t)(86u << 20));               // 6*128 floats
  float* sh0 = sc0 + 128;
  float* sc1 = sc0 + 256;
  float* sh1 = sc0 + 384;
  float* sc2 = sc0 + 512;
  float* sh2 = sc0 + 640;

  fps_p0_kernel<<<1040, 256, 0, stream>>>(xyz, newxyz, points, w0, P0);
  ballquery_stats0_kernel<<<4096, 256, 0, stream>>>(xyz, newxyz, P0, w0, gidx, partials0);
  finalize_kernel<<<64, 256, 0, stream>>>(partials0, 64, 4096, g0, b0, sc0, sh0);
  p2_kernel<<<1024, 256, 0, stream>>>(xyz, newxyz, P0, gidx, w0, w1, sc0, sh0, act1, partials1);
  finalize_kernel<<<64, 256, 0, stream>>>(partials1, 64, 1024, g1, b1, sc1, sh1);
  p3_kernel<<<1024, 256, 0, stream>>>(act1, w2, sc1, sh1, partials2);
  finalize_kernel<<<128, 256, 0, stream>>>(partials2, 128, 1024, g2, b2, sc2, sh2);
  p4_kernel<<<8192, 256, 0, stream>>>(act1, w2, sc1, sh1, sc2, sh2, feats);
}

// Round 6
// 1252.488 us; speedup vs baseline: 1.1660x; 1.1660x over previous
//
#include <hip/hip_runtime.h>

#define DI static __device__ __forceinline__

typedef float v2f __attribute__((ext_vector_type(2)));

DI unsigned short f2bf(float f) {
  unsigned int u = __float_as_uint(f);
  u = (u + 0x7fffu + ((u >> 16) & 1u)) >> 16;
  return (unsigned short)u;
}
DI float bf2f(unsigned short h) { return __uint_as_float(((unsigned int)h) << 16); }

// DPP wave64 reduce steps (VALU pipe, ~2-4cyc each — replaces LDS-latency
// shfl butterfly). update_dpp(old=v, src=v, ctrl, 0xf, 0xf, false): lanes
// with invalid source keep old=v, so max/min stay correct (idempotent).
#define DPP_MAXU(v, ctrl)                                                      \
  {                                                                            \
    unsigned o_ = (unsigned)__builtin_amdgcn_update_dpp((int)(v), (int)(v),    \
                                                        (ctrl), 0xf, 0xf, false); \
    (v) = (o_ > (v)) ? o_ : (v);                                               \
  }
#define DPP_MINU(v, ctrl)                                                      \
  {                                                                            \
    unsigned o_ = (unsigned)__builtin_amdgcn_update_dpp((int)(v), (int)(v),    \
                                                        (ctrl), 0xf, 0xf, false); \
    (v) = (o_ < (v)) ? o_ : (v);                                               \
  }

// ---------------------------------------------------------------------------
// FPS: one block per batch, 512 threads, 8 points/thread in registers (v2f
// pairs — validated bit-exact in r5). Distance arithmetic is the exact rn
// sequence verified in r3: d = ((dx*dx+dy*dy)+dz*dz), contraction off.
// Argmax per wave: DPP u32-max on dist bits (positive floats order as uint),
// readlane 63 -> wave max; then DPP u32-min on index among matching lanes
// (exact jnp.argmax first-index tie-break). Cross-wave: 8 parity slots of
// packed (dist<<32)|~idx, 3-level select tree, one barrier per step.
// ---------------------------------------------------------------------------
__global__ __launch_bounds__(512) void fps_kernel(const float* __restrict__ xyz,
                                                  float* __restrict__ newxyz) {
  const int b = blockIdx.x;
  const int t = threadIdx.x;
  const int lane = t & 63, wid = t >> 6;  // 8 waves
  const float* X = xyz + (size_t)b * 4096 * 3;
  __shared__ float XL[4096 * 3];
  __shared__ unsigned long long slot[2][8];
  for (int idx = t; idx < 12288; idx += 512) XL[idx] = X[idx];
  v2f px[4], py[4], pz[4], dist[4];
#pragma unroll
  for (int q = 0; q < 4; ++q) {
    int i0 = t + (q << 10);  // point t + 1024q
    int i1 = i0 + 512;       // point t + 1024q + 512
    px[q] = (v2f){X[i0 * 3 + 0], X[i1 * 3 + 0]};
    py[q] = (v2f){X[i0 * 3 + 1], X[i1 * 3 + 1]};
    pz[q] = (v2f){X[i0 * 3 + 2], X[i1 * 3 + 2]};
    dist[q] = (v2f){3.402823466e38f, 3.402823466e38f};
  }
  __syncthreads();
  float cx = XL[0], cy = XL[1], cz = XL[2];  // farthest = 0 initially
  float* out = newxyz + (size_t)b * 1024 * 3;
  for (int s = 0; s < 1024; ++s) {
    if (t == 0) { out[s * 3 + 0] = cx; out[s * 3 + 1] = cy; out[s * 3 + 2] = cz; }
    float bv = -1.0f;
    unsigned int bi = 0;
    v2f cxv = (v2f){cx, cx}, cyv = (v2f){cy, cy}, czv = (v2f){cz, cz};
#pragma unroll
    for (int q = 0; q < 4; ++q) {
#pragma clang fp contract(off)
      v2f dx = px[q] - cxv;
      v2f dy = py[q] - cyv;
      v2f dz = pz[q] - czv;
      v2f d = (dx * dx + dy * dy) + dz * dz;  // elementwise rn, no contraction
#if __has_builtin(__builtin_elementwise_min)
      v2f nd = __builtin_elementwise_min(dist[q], d);
#else
      v2f nd;
      nd.x = fminf(dist[q].x, d.x);
      nd.y = fminf(dist[q].y, d.y);
#endif
      dist[q] = nd;
      float n0 = nd.x, n1 = nd.y;
      // ascending index order within thread; strict > keeps earliest
      bool c0 = (n0 > bv);
      bv = c0 ? n0 : bv;
      bi = c0 ? (unsigned)(t + (q << 10)) : bi;
      bool c1 = (n1 > bv);
      bv = c1 ? n1 : bv;
      bi = c1 ? (unsigned)(t + (q << 10) + 512) : bi;
    }
    // ---- phase 1: wave max of dist bits (DPP, VALU-latency) ----
    unsigned vb = __float_as_uint(bv);  // bv >= 0 -> uint order == float order
    unsigned m = vb;
    DPP_MAXU(m, 0x111);  // row_shr:1
    DPP_MAXU(m, 0x112);  // row_shr:2
    DPP_MAXU(m, 0x114);  // row_shr:4
    DPP_MAXU(m, 0x118);  // row_shr:8
    DPP_MAXU(m, 0x142);  // row_bcast:15
    DPP_MAXU(m, 0x143);  // row_bcast:31
    unsigned wmax = (unsigned)__builtin_amdgcn_readlane((int)m, 63);
    // ---- phase 2: wave min index among lanes at the max ----
    unsigned ik = (vb == wmax) ? bi : 0xFFFFFFFFu;
    DPP_MINU(ik, 0x111);
    DPP_MINU(ik, 0x112);
    DPP_MINU(ik, 0x114);
    DPP_MINU(ik, 0x118);
    DPP_MINU(ik, 0x142);
    DPP_MINU(ik, 0x143);
    unsigned widx = (unsigned)__builtin_amdgcn_readlane((int)ik, 63);
    const int p = s & 1;
    if (lane == 0)
      slot[p][wid] = ((unsigned long long)wmax << 32) | (unsigned long long)(~widx);
    __syncthreads();
    // 8-way block winner: max key == max dist, tie -> min idx (bigger ~idx)
    unsigned long long k0 = slot[p][0], k1 = slot[p][1], k2 = slot[p][2], k3 = slot[p][3];
    unsigned long long k4 = slot[p][4], k5 = slot[p][5], k6 = slot[p][6], k7 = slot[p][7];
    unsigned long long m01 = (k0 >= k1) ? k0 : k1;
    unsigned long long m23 = (k2 >= k3) ? k2 : k3;
    unsigned long long m45 = (k4 >= k5) ? k4 : k5;
    unsigned long long m67 = (k6 >= k7) ? k6 : k7;
    unsigned long long ma = (m01 >= m23) ? m01 : m23;
    unsigned long long mb = (m45 >= m67) ? m45 : m67;
    unsigned long long win = (ma >= mb) ? ma : mb;
    int fi = (int)(~(unsigned int)win);  // winner index in [0,4095]
    cx = XL[fi * 3 + 0];
    cy = XL[fi * 3 + 1];
    cz = XL[fi * 3 + 2];
  }
}

// ---------------------------------------------------------------------------
// P0[b][n][o] = sum_c W0[o][3+c] * points[b][c][n]   (pushes mm0 through gather)
// block = 64 n x 64 o, 256 threads, register 4x4 tiles. grid = 16*64 = 1024.
// ---------------------------------------------------------------------------
__global__ __launch_bounds__(256) void p0_kernel(const float* __restrict__ points,
                                                 const float* __restrict__ w0,
                                                 float* __restrict__ P0) {
  const int b = blockIdx.x >> 6;
  const int n0 = (blockIdx.x & 63) << 6;
  const int t = threadIdx.x;
  __shared__ float W[64][64];  // [c][o]
  for (int idx = t; idx < 4096; idx += 256) {
    int c = idx >> 6, o = idx & 63;
    W[c][o] = w0[o * 67 + 3 + c];
  }
  __syncthreads();
  const int i = t >> 4, j = t & 15;
  const float* Pb = points + (size_t)b * 64 * 4096 + n0 + 4 * i;
  float acc[4][4] = {};
  for (int c = 0; c < 64; ++c) {
    float4 xv = *(const float4*)(Pb + (size_t)c * 4096);
    float4 wv = *(const float4*)&W[c][4 * j];
    float xr[4] = {xv.x, xv.y, xv.z, xv.w};
    float wr[4] = {wv.x, wv.y, wv.z, wv.w};
#pragma unroll
    for (int rr = 0; rr < 4; ++rr)
#pragma unroll
      for (int oi = 0; oi < 4; ++oi) acc[rr][oi] = fmaf(xr[rr], wr[oi], acc[rr][oi]);
  }
#pragma unroll
  for (int rr = 0; rr < 4; ++rr) {
    float4 vv = make_float4(acc[rr][0], acc[rr][1], acc[rr][2], acc[rr][3]);
    *(float4*)(P0 + ((size_t)b * 4096 + n0 + 4 * i + rr) * 64 + 4 * j) = vv;
  }
}

// ---------------------------------------------------------------------------
// Ball query fused with layer-0 stats accumulation.
// sqr emulates XLA-CPU fp32 arithmetic of the reference (VERIFIED r3):
//   dot  = fma chain over d; cs/xs = plain rn; sqr = rn((cs+xs) - 2*dot)
// One wave per group, 4 groups per block, grid = 4096.
// ---------------------------------------------------------------------------
__global__ __launch_bounds__(256) void ballquery_stats0_kernel(
    const float* __restrict__ xyz, const float* __restrict__ newxyz,
    const float* __restrict__ P0, const float* __restrict__ w0,
    int* __restrict__ gidx, float* __restrict__ partials0) {
  const int t = threadIdx.x;
  const int lane = t & 63, w = t >> 6;
  const int gid = blockIdx.x * 4 + w;  // 0..16383
  const int b = gid >> 10;
  __shared__ int sel[4][32];
  __shared__ float red[4][128];
  const float* Xb = xyz + (size_t)b * 4096 * 3;
  const float cx = newxyz[(size_t)gid * 3 + 0];
  const float cy = newxyz[(size_t)gid * 3 + 1];
  const float cz = newxyz[(size_t)gid * 3 + 2];
  const float cs = __fadd_rn(__fadd_rn(__fmul_rn(cx, cx), __fmul_rn(cy, cy)), __fmul_rn(cz, cz));
  int cnt = 0, first = 0;
  bool found = false;
  for (int base = 0; base < 4096; base += 64) {
    int i = base + lane;
    float x = Xb[i * 3 + 0], y = Xb[i * 3 + 1], z = Xb[i * 3 + 2];
    float xs = __fadd_rn(__fadd_rn(__fmul_rn(x, x), __fmul_rn(y, y)), __fmul_rn(z, z));
    float dot = fmaf(cz, z, fmaf(cy, y, __fmul_rn(cx, x)));  // fma chain, d=0,1,2
    float sqr = __fsub_rn(__fadd_rn(cs, xs), __fmul_rn(2.0f, dot));
    bool ok = sqr <= 0.04f;
    unsigned long long mask = __ballot(ok);
    if (!found && mask != 0ull) { first = base + __builtin_ctzll(mask); found = true; }
    int pre = __popcll(mask & ((1ull << lane) - 1ull));
    int pos = cnt + pre;
    if (ok && pos < 32) sel[w][pos] = i;
    cnt += (int)__popcll(mask);
    if (cnt >= 32) break;
  }
  if (cnt < 32) {
    int pad = found ? first : 0;
    for (int p = cnt + lane; p < 32; p += 64) sel[w][p] = pad;
  }
  __syncthreads();
  if (lane < 32) gidx[(size_t)gid * 32 + lane] = sel[w][lane];
  // ---- stats for act0 (pre-BN layer0 output): lane = channel c ----
  const int c = lane;
  float wx = w0[c * 67 + 0], wy = w0[c * 67 + 1], wz = w0[c * 67 + 2];
  float ssum = 0.f, ssq = 0.f;
  const float* P0b = P0 + (size_t)b * 4096 * 64;
  for (int k = 0; k < 32; ++k) {
    int g = sel[w][k];
    float gx = Xb[g * 3 + 0] - cx, gy = Xb[g * 3 + 1] - cy, gz = Xb[g * 3 + 2] - cz;
    float a0 = fmaf(wx, gx, fmaf(wy, gy, fmaf(wz, gz, P0b[(size_t)g * 64 + c])));
    ssum += a0;
    ssq = fmaf(a0, a0, ssq);
  }
  red[w][c] = ssum;
  red[w][c + 64] = ssq;
  __syncthreads();
  if (t < 128) {
    float acc = red[0][t] + red[1][t] + red[2][t] + red[3][t];
    partials0[(size_t)t * 4096 + blockIdx.x] = acc;
  }
}

// ---------------------------------------------------------------------------
// finalize BN stats: scale = g*rsqrt(var+eps), shift = b - mean*scale
// ---------------------------------------------------------------------------
__global__ __launch_bounds__(256) void finalize_kernel(
    const float* __restrict__ partials, int C, int nblk,
    const float* __restrict__ gamma, const float* __restrict__ beta,
    float* __restrict__ scale, float* __restrict__ shift) {
  const int c = blockIdx.x, t = threadIdx.x;
  double s1 = 0.0, s2 = 0.0;
  for (int k = t; k < nblk; k += 256) {
    s1 += (double)partials[(size_t)c * nblk + k];
    s2 += (double)partials[(size_t)(C + c) * nblk + k];
  }
  __shared__ double r1[256], r2[256];
  r1[t] = s1;
  r2[t] = s2;
  __syncthreads();
  for (int off = 128; off > 0; off >>= 1) {
    if (t < off) { r1[t] += r1[t + off]; r2[t] += r2[t + off]; }
    __syncthreads();
  }
  if (t == 0) {
    const double M = 524288.0;
    double mean = r1[0] / M;
    double var = r2[0] / M - mean * mean;
    if (var < 0.0) var = 0.0;
    float sc = gamma[c] * (float)(1.0 / sqrt(var + 1e-5));
    scale[c] = sc;
    shift[c] = beta[c] - (float)mean * sc;
  }
}

// ---------------------------------------------------------------------------
// P2: act1_raw = W1 * relu(bn0(act0)), store bf16, accumulate stats1.
// grid = 1024 blocks x 8 tiles x 64 rows. 256 thr: 4-row x 4-out register tile.
// ---------------------------------------------------------------------------
__global__ __launch_bounds__(256) void p2_kernel(
    const float* __restrict__ xyz, const float* __restrict__ newxyz,
    const float* __restrict__ P0, const int* __restrict__ gidx,
    const float* __restrict__ w0, const float* __restrict__ w1,
    const float* __restrict__ sc0g, const float* __restrict__ sh0g,
    unsigned short* __restrict__ act1, float* __restrict__ partials1) {
  __shared__ float W1s[64][64];  // [c][o]
  __shared__ float Xs[64][64];   // [c][row]
  __shared__ float w0x[64], w0y[64], w0z[64], sc0[64], sh0[64];
  __shared__ float Sred[256][8];
  const int t = threadIdx.x;
  for (int idx = t; idx < 4096; idx += 256) {
    int c = idx >> 6, o = idx & 63;
    W1s[c][o] = w1[o * 64 + c];
  }
  if (t < 64) {
    w0x[t] = w0[t * 67 + 0];
    w0y[t] = w0[t * 67 + 1];
    w0z[t] = w0[t * 67 + 2];
    sc0[t] = sc0g[t];
    sh0[t] = sh0g[t];
  }
  __syncthreads();
  const int i = t >> 4, j = t & 15;
  const int rl = t >> 2, cq = t & 3;
  float ssum[4] = {}, ssq[4] = {};
  for (int tile = 0; tile < 8; ++tile) {
    const int rowbase = (blockIdx.x * 8 + tile) << 6;
    {
      int r = rowbase + rl;
      int b = r >> 15, s = (r >> 5) & 1023;
      int g = gidx[r];
      const float* Pt = xyz + ((size_t)b * 4096 + g) * 3;
      const float* Ct = newxyz + ((size_t)b * 1024 + s) * 3;
      float dx = Pt[0] - Ct[0], dy = Pt[1] - Ct[1], dz = Pt[2] - Ct[2];
      const float* p0r = P0 + ((size_t)b * 4096 + g) * 64 + cq * 16;
      const float4* p4 = (const float4*)p0r;
      float4 a0 = p4[0], a1 = p4[1], a2 = p4[2], a3 = p4[3];
      float pv[16] = {a0.x, a0.y, a0.z, a0.w, a1.x, a1.y, a1.z, a1.w,
                      a2.x, a2.y, a2.z, a2.w, a3.x, a3.y, a3.z, a3.w};
#pragma unroll
      for (int cc = 0; cc < 16; ++cc) {
        int c = cq * 16 + cc;
        float a = fmaf(w0x[c], dx, fmaf(w0y[c], dy, fmaf(w0z[c], dz, pv[cc])));
        Xs[c][rl] = fmaxf(0.f, fmaf(a, sc0[c], sh0[c]));
      }
    }
    __syncthreads();
    float acc[4][4] = {};
#pragma unroll 4
    for (int c = 0; c < 64; ++c) {
      float4 xv = *(const float4*)&Xs[c][4 * i];
      float4 wv = *(const float4*)&W1s[c][4 * j];
      float xr[4] = {xv.x, xv.y, xv.z, xv.w};
      float wr[4] = {wv.x, wv.y, wv.z, wv.w};
#pragma unroll
      for (int rr = 0; rr < 4; ++rr)
#pragma unroll
        for (int oi = 0; oi < 4; ++oi) acc[rr][oi] = fmaf(xr[rr], wr[oi], acc[rr][oi]);
    }
#pragma unroll
    for (int rr = 0; rr < 4; ++rr) {
      size_t r = (size_t)rowbase + 4 * i + rr;
      ushort4 pk;
      float y0 = acc[rr][0], y1 = acc[rr][1], y2 = acc[rr][2], y3 = acc[rr][3];
      ssum[0] += y0; ssq[0] = fmaf(y0, y0, ssq[0]);
      ssum[1] += y1; ssq[1] = fmaf(y1, y1, ssq[1]);
      ssum[2] += y2; ssq[2] = fmaf(y2, y2, ssq[2]);
      ssum[3] += y3; ssq[3] = fmaf(y3, y3, ssq[3]);
      pk.x = f2bf(y0); pk.y = f2bf(y1); pk.z = f2bf(y2); pk.w = f2bf(y3);
      *(ushort4*)(act1 + r * 64 + 4 * j) = pk;
    }
    __syncthreads();
  }
#pragma unroll
  for (int oi = 0; oi < 4; ++oi) { Sred[t][oi] = ssum[oi]; Sred[t][4 + oi] = ssq[oi]; }
  __syncthreads();
  if (t < 64) {
    int jj = t >> 2, oi = t & 3;
    float s1 = 0.f, s2 = 0.f;
#pragma unroll
    for (int ii = 0; ii < 16; ++ii) {
      s1 += Sred[ii * 16 + jj][oi];
      s2 += Sred[ii * 16 + jj][4 + oi];
    }
    partials1[(size_t)t * 1024 + blockIdx.x] = s1;
    partials1[(size_t)(64 + t) * 1024 + blockIdx.x] = s2;
  }
}

// ---------------------------------------------------------------------------
// P3: stats of act2_raw = W2 * relu(bn1(act1)) (no store; P4 recomputes).
// ---------------------------------------------------------------------------
__global__ __launch_bounds__(256) void p3_kernel(
    const unsigned short* __restrict__ act1, const float* __restrict__ w2,
    const float* __restrict__ sc1g, const float* __restrict__ sh1g,
    float* __restrict__ partials2) {
  __shared__ float W2s[64][128];  // [c][o]
  __shared__ union US { float Xs[64][64]; float Sred[256][16]; } u;
  __shared__ float sc1[64], sh1[64];
  const int t = threadIdx.x;
  for (int idx = t; idx < 8192; idx += 256) {
    int c = idx >> 7, o = idx & 127;
    W2s[c][o] = w2[o * 64 + c];
  }
  if (t < 64) { sc1[t] = sc1g[t]; sh1[t] = sh1g[t]; }
  __syncthreads();
  const int i = t >> 4, j = t & 15;
  const int rl = t >> 2, cq = t & 3;
  float ssum[8] = {}, ssq[8] = {};
  for (int tile = 0; tile < 8; ++tile) {
    const int rowbase = (blockIdx.x * 8 + tile) << 6;
    {
      size_t r = (size_t)rowbase + rl;
      const uint4* pr = (const uint4*)(act1 + r * 64 + cq * 16);
      uint4 aa = pr[0], bb = pr[1];
      unsigned int uu[8] = {aa.x, aa.y, aa.z, aa.w, bb.x, bb.y, bb.z, bb.w};
#pragma unroll
      for (int q = 0; q < 8; ++q) {
        int c = cq * 16 + 2 * q;
        float v0 = bf2f((unsigned short)(uu[q] & 0xffffu));
        float v1 = bf2f((unsigned short)(uu[q] >> 16));
        u.Xs[c][rl] = fmaxf(0.f, fmaf(v0, sc1[c], sh1[c]));
        u.Xs[c + 1][rl] = fmaxf(0.f, fmaf(v1, sc1[c + 1], sh1[c + 1]));
      }
    }
    __syncthreads();
    float acc[4][8] = {};
#pragma unroll 2
    for (int c = 0; c < 64; ++c) {
      float4 xv = *(const float4*)&u.Xs[c][4 * i];
      float4 wa = *(const float4*)&W2s[c][4 * j];
      float4 wb = *(const float4*)&W2s[c][64 + 4 * j];
      float xr[4] = {xv.x, xv.y, xv.z, xv.w};
      float wr[8] = {wa.x, wa.y, wa.z, wa.w, wb.x, wb.y, wb.z, wb.w};
#pragma unroll
      for (int rr = 0; rr < 4; ++rr)
#pragma unroll
        for (int q = 0; q < 8; ++q) acc[rr][q] = fmaf(xr[rr], wr[q], acc[rr][q]);
    }
#pragma unroll
    for (int rr = 0; rr < 4; ++rr)
#pragma unroll
      for (int q = 0; q < 8; ++q) {
        float y = acc[rr][q];
        ssum[q] += y;
        ssq[q] = fmaf(y, y, ssq[q]);
      }
    __syncthreads();
  }
#pragma unroll
  for (int q = 0; q < 8; ++q) { u.Sred[t][q] = ssum[q]; u.Sred[t][8 + q] = ssq[q]; }
  __syncthreads();
  if (t < 128) {
    int o = t;
    int jj = (o & 63) >> 2, oh = o >> 6, oi = o & 3, slot = oh * 4 + oi;
    float s1 = 0.f, s2 = 0.f;
#pragma unroll
    for (int ii = 0; ii < 16; ++ii) {
      s1 += u.Sred[ii * 16 + jj][slot];
      s2 += u.Sred[ii * 16 + jj][8 + slot];
    }
    partials2[(size_t)o * 1024 + blockIdx.x] = s1;
    partials2[(size_t)(128 + o) * 1024 + blockIdx.x] = s2;
  }
}

// ---------------------------------------------------------------------------
// P4: recompute act2, bn2+relu, max over K=32, write feats[b][o][s].
// grid = 8192 blocks, 1 tile = 64 rows = 2 groups each.
// ---------------------------------------------------------------------------
__global__ __launch_bounds__(256) void p4_kernel(
    const unsigned short* __restrict__ act1, const float* __restrict__ w2,
    const float* __restrict__ sc1g, const float* __restrict__ sh1g,
    const float* __restrict__ sc2g, const float* __restrict__ sh2g,
    float* __restrict__ feats) {
  __shared__ float W2s[64][128];
  __shared__ float Xs[64][64];
  __shared__ float Mred[16][132];  // padded stride vs 128 to dodge bank conflicts
  __shared__ float sc1[64], sh1[64], sc2[128], sh2[128];
  const int t = threadIdx.x;
  for (int idx = t; idx < 8192; idx += 256) {
    int c = idx >> 7, o = idx & 127;
    W2s[c][o] = w2[o * 64 + c];
  }
  if (t < 64) { sc1[t] = sc1g[t]; sh1[t] = sh1g[t]; }
  if (t < 128) { sc2[t] = sc2g[t]; sh2[t] = sh2g[t]; }
  __syncthreads();
  const int i = t >> 4, j = t & 15;
  const int rl = t >> 2, cq = t & 3;
  const int rowbase = blockIdx.x << 6;
  {
    size_t r = (size_t)rowbase + rl;
    const uint4* pr = (const uint4*)(act1 + r * 64 + cq * 16);
    uint4 aa = pr[0], bb = pr[1];
    unsigned int uu[8] = {aa.x, aa.y, aa.z, aa.w, bb.x, bb.y, bb.z, bb.w};
#pragma unroll
    for (int q = 0; q < 8; ++q) {
      int c = cq * 16 + 2 * q;
      float v0 = bf2f((unsigned short)(uu[q] & 0xffffu));
      float v1 = bf2f((unsigned short)(uu[q] >> 16));
      Xs[c][rl] = fmaxf(0.f, fmaf(v0, sc1[c], sh1[c]));
      Xs[c + 1][rl] = fmaxf(0.f, fmaf(v1, sc1[c + 1], sh1[c + 1]));
    }
  }
  __syncthreads();
  float acc[4][8] = {};
#pragma unroll 2
  for (int c = 0; c < 64; ++c) {
    float4 xv = *(const float4*)&Xs[c][4 * i];
    float4 wa = *(const float4*)&W2s[c][4 * j];
    float4 wb = *(const float4*)&W2s[c][64 + 4 * j];
    float xr[4] = {xv.x, xv.y, xv.z, xv.w};
    float wr[8] = {wa.x, wa.y, wa.z, wa.w, wb.x, wb.y, wb.z, wb.w};
#pragma unroll
    for (int rr = 0; rr < 4; ++rr)
#pragma unroll
      for (int q = 0; q < 8; ++q) acc[rr][q] = fmaf(xr[rr], wr[q], acc[rr][q]);
  }
  // rows 4i..4i+3 are all in group (i>>3); per-thread max over them.
#pragma unroll
  for (int q = 0; q < 8; ++q) {
    int oh = q >> 2, oi = q & 3;
    int o = 4 * j + 64 * oh + oi;
    float m = 0.f;  // relu output >= 0
#pragma unroll
    for (int rr = 0; rr < 4; ++rr) {
      float v = fmaxf(0.f, fmaf(acc[rr][q], sc2[o], sh2[o]));
      m = fmaxf(m, v);
    }
    Mred[i][o] = m;
  }
  __syncthreads();
  {
    int o = t & 127, g = t >> 7;
    float v = 0.f;
#pragma unroll
    for (int ii = 0; ii < 8; ++ii) v = fmaxf(v, Mred[g * 8 + ii][o]);
    int b = rowbase >> 15;
    int s = ((rowbase >> 5) & 1023) + g;
    feats[(size_t)b * 131072 + (size_t)o * 1024 + s] = v;
  }
}

// ---------------------------------------------------------------------------
extern "C" void kernel_launch(void* const* d_in, const int* in_sizes, int n_in,
                              void* d_out, int out_size, void* d_ws, size_t ws_size,
                              hipStream_t stream) {
  const float* xyz = (const float*)d_in[0];
  const float* points = (const float*)d_in[1];
  const float* w0 = (const float*)d_in[2];
  const float* g0 = (const float*)d_in[3];
  const float* b0 = (const float*)d_in[4];
  const float* w1 = (const float*)d_in[5];
  const float* g1 = (const float*)d_in[6];
  const float* b1 = (const float*)d_in[7];
  const float* w2 = (const float*)d_in[8];
  const float* g2 = (const float*)d_in[9];
  const float* b2 = (const float*)d_in[10];

  float* out = (float*)d_out;
  float* newxyz = out;            // (16,1024,3)
  float* feats = out + 49152;     // (16,128,1024)

  char* ws = (char*)d_ws;
  float* P0 = (float*)ws;                                        // 16 MB  [b][n][64]
  int* gidx = (int*)(ws + (size_t)(16u << 20));                  // 2 MB
  unsigned short* act1 = (unsigned short*)(ws + (size_t)(18u << 20));  // 64 MB bf16
  float* partials0 = (float*)(ws + (size_t)(82u << 20));         // 2 MB   [128][4096]
  float* partials1 = (float*)(ws + (size_t)(84u << 20));         // 0.5 MB [128][1024]
  float* partials2 = (float*)(ws + (size_t)(85u << 20));         // 1 MB   [256][1024]
  float* sc0 = (float*)(ws + (size_t)(86u << 20));               // 6*128 floats
  float* sh0 = sc0 + 128;
  float* sc1 = sc0 + 256;
  float* sh1 = sc0 + 384;
  float* sc2 = sc0 + 512;
  float* sh2 = sc0 + 640;

  fps_kernel<<<16, 512, 0, stream>>>(xyz, newxyz);
  p0_kernel<<<1024, 256, 0, stream>>>(points, w0, P0);
  ballquery_stats0_kernel<<<4096, 256, 0, stream>>>(xyz, newxyz, P0, w0, gidx, partials0);
  finalize_kernel<<<64, 256, 0, stream>>>(partials0, 64, 4096, g0, b0, sc0, sh0);
  p2_kernel<<<1024, 256, 0, stream>>>(xyz, newxyz, P0, gidx, w0, w1, sc0, sh0, act1, partials1);
  finalize_kernel<<<64, 256, 0, stream>>>(partials1, 64, 1024, g1, b1, sc1, sh1);
  p3_kernel<<<1024, 256, 0, stream>>>(act1, w2, sc1, sh1, partials2);
  finalize_kernel<<<128, 256, 0, stream>>>(partials2, 128, 1024, g2, b2, sc2, sh2);
  p4_kernel<<<8192, 256, 0, stream>>>(act1, w2, sc1, sh1, sc2, sh2, feats);
}

// Round 7
// 1171.018 us; speedup vs baseline: 1.2472x; 1.0696x over previous
//
#include <hip/hip_runtime.h>

#define DI static __device__ __forceinline__

typedef float v2f __attribute__((ext_vector_type(2)));

DI unsigned short f2bf(float f) {
  unsigned int u = __float_as_uint(f);
  u = (u + 0x7fffu + ((u >> 16) & 1u)) >> 16;
  return (unsigned short)u;
}
DI float bf2f(unsigned short h) { return __uint_as_float(((unsigned int)h) << 16); }

// DPP wave64 reduce steps (VALU pipe). update_dpp(old=v, src=v, ctrl, 0xf,
// 0xf, false): lanes with invalid source keep old=v (idempotent for max/min).
#define DPP_MAXU(v, ctrl)                                                      \
  {                                                                            \
    unsigned o_ = (unsigned)__builtin_amdgcn_update_dpp((int)(v), (int)(v),    \
                                                        (ctrl), 0xf, 0xf, false); \
    (v) = (o_ > (v)) ? o_ : (v);                                               \
  }
#define DPP_MINU(v, ctrl)                                                      \
  {                                                                            \
    unsigned o_ = (unsigned)__builtin_amdgcn_update_dpp((int)(v), (int)(v),    \
                                                        (ctrl), 0xf, 0xf, false); \
    (v) = (o_ < (v)) ? o_ : (v);                                               \
  }

// ---------------------------------------------------------------------------
// FPS: one block per batch, 256 threads (4 waves), 16 points/thread as 8 v2f.
// Distance arithmetic = exact rn sequence verified bit-exact in r3:
//   d = ((dx*dx+dy*dy)+dz*dz), contraction off. DO NOT TOUCH.
// r7 changes (latency): NO global stores inside the step loop (winner index
// appended to LDS FI[]; centroids written once at the end) -> pre-barrier
// drain is lgkm-only, not vmcnt(0). 4 waves (cheaper barrier, 32B slot read).
// Argmax semantics identical: DPP u32-max on dist bits, then DPP u32-min on
// index among max lanes (jnp.argmax first-index tie-break); cross-wave via
// packed (dist<<32)|~idx parity slots, one barrier per step.
// ---------------------------------------------------------------------------
__global__ __launch_bounds__(256) void fps_kernel(const float* __restrict__ xyz,
                                                  float* __restrict__ newxyz) {
  const int b = blockIdx.x;
  const int t = threadIdx.x;
  const int lane = t & 63, wid = t >> 6;  // 4 waves
  const float* X = xyz + (size_t)b * 4096 * 3;
  __shared__ float XL[4096 * 3];
  __shared__ int FI[1024];
  __shared__ unsigned long long slot[2][4];
  for (int idx = t; idx < 12288; idx += 256) XL[idx] = X[idx];
  v2f px[8], py[8], pz[8], dist[8];
#pragma unroll
  for (int q = 0; q < 8; ++q) {
    int i0 = t + (q << 9);  // t + 512q
    int i1 = i0 + 256;      // t + 512q + 256  (ascending with q)
    px[q] = (v2f){X[i0 * 3 + 0], X[i1 * 3 + 0]};
    py[q] = (v2f){X[i0 * 3 + 1], X[i1 * 3 + 1]};
    pz[q] = (v2f){X[i0 * 3 + 2], X[i1 * 3 + 2]};
    dist[q] = (v2f){3.402823466e38f, 3.402823466e38f};
  }
  __syncthreads();
  float cx = XL[0], cy = XL[1], cz = XL[2];  // farthest = 0 initially
  int fi = 0;
  for (int s = 0; s < 1024; ++s) {
    if (t == 0) FI[s] = fi;  // centroid index used this step (LDS, cheap)
    float bv = -1.0f;
    unsigned int bi = 0;
    v2f cxv = (v2f){cx, cx}, cyv = (v2f){cy, cy}, czv = (v2f){cz, cz};
#pragma unroll
    for (int q = 0; q < 8; ++q) {
#pragma clang fp contract(off)
      v2f dx = px[q] - cxv;
      v2f dy = py[q] - cyv;
      v2f dz = pz[q] - czv;
      v2f d = (dx * dx + dy * dy) + dz * dz;  // elementwise rn, no contraction
#if __has_builtin(__builtin_elementwise_min)
      v2f nd = __builtin_elementwise_min(dist[q], d);
#else
      v2f nd;
      nd.x = fminf(dist[q].x, d.x);
      nd.y = fminf(dist[q].y, d.y);
#endif
      dist[q] = nd;
      float n0 = nd.x, n1 = nd.y;
      // ascending index order within thread; strict > keeps earliest
      bool c0 = (n0 > bv);
      bv = c0 ? n0 : bv;
      bi = c0 ? (unsigned)(t + (q << 9)) : bi;
      bool c1 = (n1 > bv);
      bv = c1 ? n1 : bv;
      bi = c1 ? (unsigned)(t + (q << 9) + 256) : bi;
    }
    // ---- phase 1: wave max of dist bits (DPP, VALU-latency) ----
    unsigned vb = __float_as_uint(bv);  // bv >= 0 -> uint order == float order
    unsigned m = vb;
    DPP_MAXU(m, 0x111);  // row_shr:1
    DPP_MAXU(m, 0x112);  // row_shr:2
    DPP_MAXU(m, 0x114);  // row_shr:4
    DPP_MAXU(m, 0x118);  // row_shr:8
    DPP_MAXU(m, 0x142);  // row_bcast:15
    DPP_MAXU(m, 0x143);  // row_bcast:31
    unsigned wmax = (unsigned)__builtin_amdgcn_readlane((int)m, 63);
    // ---- phase 2: wave min index among lanes at the max ----
    unsigned ik = (vb == wmax) ? bi : 0xFFFFFFFFu;
    DPP_MINU(ik, 0x111);
    DPP_MINU(ik, 0x112);
    DPP_MINU(ik, 0x114);
    DPP_MINU(ik, 0x118);
    DPP_MINU(ik, 0x142);
    DPP_MINU(ik, 0x143);
    unsigned widx = (unsigned)__builtin_amdgcn_readlane((int)ik, 63);
    const int p = s & 1;
    if (lane == 0)
      slot[p][wid] = ((unsigned long long)wmax << 32) | (unsigned long long)(~widx);
    __syncthreads();
    // 4-way block winner: max key == max dist, tie -> min idx (bigger ~idx)
    unsigned long long k0 = slot[p][0], k1 = slot[p][1];
    unsigned long long k2 = slot[p][2], k3 = slot[p][3];
    unsigned long long m01 = (k0 >= k1) ? k0 : k1;
    unsigned long long m23 = (k2 >= k3) ? k2 : k3;
    unsigned long long win = (m01 >= m23) ? m01 : m23;
    fi = (int)(~(unsigned int)win);  // winner index in [0,4095]
    cx = XL[fi * 3 + 0];
    cy = XL[fi * 3 + 1];
    cz = XL[fi * 3 + 2];
  }
  __syncthreads();
  // batched centroid write-out (coalesced-ish, once per kernel)
  float* out = newxyz + (size_t)b * 1024 * 3;
  for (int s2 = t; s2 < 1024; s2 += 256) {
    int f = FI[s2];
    out[s2 * 3 + 0] = XL[f * 3 + 0];
    out[s2 * 3 + 1] = XL[f * 3 + 1];
    out[s2 * 3 + 2] = XL[f * 3 + 2];
  }
}

// ---------------------------------------------------------------------------
// P0[b][n][o] = sum_c W0[o][3+c] * points[b][c][n]   (pushes mm0 through gather)
// block = 64 n x 64 o, 256 threads, register 4x4 tiles. grid = 16*64 = 1024.
// ---------------------------------------------------------------------------
__global__ __launch_bounds__(256) void p0_kernel(const float* __restrict__ points,
                                                 const float* __restrict__ w0,
                                                 float* __restrict__ P0) {
  const int b = blockIdx.x >> 6;
  const int n0 = (blockIdx.x & 63) << 6;
  const int t = threadIdx.x;
  __shared__ float W[64][64];  // [c][o]
  for (int idx = t; idx < 4096; idx += 256) {
    int c = idx >> 6, o = idx & 63;
    W[c][o] = w0[o * 67 + 3 + c];
  }
  __syncthreads();
  const int i = t >> 4, j = t & 15;
  const float* Pb = points + (size_t)b * 64 * 4096 + n0 + 4 * i;
  float acc[4][4] = {};
  for (int c = 0; c < 64; ++c) {
    float4 xv = *(const float4*)(Pb + (size_t)c * 4096);
    float4 wv = *(const float4*)&W[c][4 * j];
    float xr[4] = {xv.x, xv.y, xv.z, xv.w};
    float wr[4] = {wv.x, wv.y, wv.z, wv.w};
#pragma unroll
    for (int rr = 0; rr < 4; ++rr)
#pragma unroll
      for (int oi = 0; oi < 4; ++oi) acc[rr][oi] = fmaf(xr[rr], wr[oi], acc[rr][oi]);
  }
#pragma unroll
  for (int rr = 0; rr < 4; ++rr) {
    float4 vv = make_float4(acc[rr][0], acc[rr][1], acc[rr][2], acc[rr][3]);
    *(float4*)(P0 + ((size_t)b * 4096 + n0 + 4 * i + rr) * 64 + 4 * j) = vv;
  }
}

// ---------------------------------------------------------------------------
// Ball query fused with layer-0 stats accumulation.
// sqr emulates XLA-CPU fp32 arithmetic of the reference (VERIFIED r3):
//   dot  = fma chain over d; cs/xs = plain rn; sqr = rn((cs+xs) - 2*dot)
// One wave per group, 4 groups per block, grid = 4096.
// ---------------------------------------------------------------------------
__global__ __launch_bounds__(256) void ballquery_stats0_kernel(
    const float* __restrict__ xyz, const float* __restrict__ newxyz,
    const float* __restrict__ P0, const float* __restrict__ w0,
    int* __restrict__ gidx, float* __restrict__ partials0) {
  const int t = threadIdx.x;
  const int lane = t & 63, w = t >> 6;
  const int gid = blockIdx.x * 4 + w;  // 0..16383
  const int b = gid >> 10;
  __shared__ int sel[4][32];
  __shared__ float red[4][128];
  const float* Xb = xyz + (size_t)b * 4096 * 3;
  const float cx = newxyz[(size_t)gid * 3 + 0];
  const float cy = newxyz[(size_t)gid * 3 + 1];
  const float cz = newxyz[(size_t)gid * 3 + 2];
  const float cs = __fadd_rn(__fadd_rn(__fmul_rn(cx, cx), __fmul_rn(cy, cy)), __fmul_rn(cz, cz));
  int cnt = 0, first = 0;
  bool found = false;
  for (int base = 0; base < 4096; base += 64) {
    int i = base + lane;
    float x = Xb[i * 3 + 0], y = Xb[i * 3 + 1], z = Xb[i * 3 + 2];
    float xs = __fadd_rn(__fadd_rn(__fmul_rn(x, x), __fmul_rn(y, y)), __fmul_rn(z, z));
    float dot = fmaf(cz, z, fmaf(cy, y, __fmul_rn(cx, x)));  // fma chain, d=0,1,2
    float sqr = __fsub_rn(__fadd_rn(cs, xs), __fmul_rn(2.0f, dot));
    bool ok = sqr <= 0.04f;
    unsigned long long mask = __ballot(ok);
    if (!found && mask != 0ull) { first = base + __builtin_ctzll(mask); found = true; }
    int pre = __popcll(mask & ((1ull << lane) - 1ull));
    int pos = cnt + pre;
    if (ok && pos < 32) sel[w][pos] = i;
    cnt += (int)__popcll(mask);
    if (cnt >= 32) break;
  }
  if (cnt < 32) {
    int pad = found ? first : 0;
    for (int p = cnt + lane; p < 32; p += 64) sel[w][p] = pad;
  }
  __syncthreads();
  if (lane < 32) gidx[(size_t)gid * 32 + lane] = sel[w][lane];
  // ---- stats for act0 (pre-BN layer0 output): lane = channel c ----
  const int c = lane;
  float wx = w0[c * 67 + 0], wy = w0[c * 67 + 1], wz = w0[c * 67 + 2];
  float ssum = 0.f, ssq = 0.f;
  const float* P0b = P0 + (size_t)b * 4096 * 64;
  for (int k = 0; k < 32; ++k) {
    int g = sel[w][k];
    float gx = Xb[g * 3 + 0] - cx, gy = Xb[g * 3 + 1] - cy, gz = Xb[g * 3 + 2] - cz;
    float a0 = fmaf(wx, gx, fmaf(wy, gy, fmaf(wz, gz, P0b[(size_t)g * 64 + c])));
    ssum += a0;
    ssq = fmaf(a0, a0, ssq);
  }
  red[w][c] = ssum;
  red[w][c + 64] = ssq;
  __syncthreads();
  if (t < 128) {
    float acc = red[0][t] + red[1][t] + red[2][t] + red[3][t];
    partials0[(size_t)t * 4096 + blockIdx.x] = acc;
  }
}

// ---------------------------------------------------------------------------
// finalize BN stats: scale = g*rsqrt(var+eps), shift = b - mean*scale
// ---------------------------------------------------------------------------
__global__ __launch_bounds__(256) void finalize_kernel(
    const float* __restrict__ partials, int C, int nblk,
    const float* __restrict__ gamma, const float* __restrict__ beta,
    float* __restrict__ scale, float* __restrict__ shift) {
  const int c = blockIdx.x, t = threadIdx.x;
  double s1 = 0.0, s2 = 0.0;
  for (int k = t; k < nblk; k += 256) {
    s1 += (double)partials[(size_t)c * nblk + k];
    s2 += (double)partials[(size_t)(C + c) * nblk + k];
  }
  __shared__ double r1[256], r2[256];
  r1[t] = s1;
  r2[t] = s2;
  __syncthreads();
  for (int off = 128; off > 0; off >>= 1) {
    if (t < off) { r1[t] += r1[t + off]; r2[t] += r2[t + off]; }
    __syncthreads();
  }
  if (t == 0) {
    const double M = 524288.0;
    double mean = r1[0] / M;
    double var = r2[0] / M - mean * mean;
    if (var < 0.0) var = 0.0;
    float sc = gamma[c] * (float)(1.0 / sqrt(var + 1e-5));
    scale[c] = sc;
    shift[c] = beta[c] - (float)mean * sc;
  }
}

// ---------------------------------------------------------------------------
// P2: act1_raw = W1 * relu(bn0(act0)), store bf16, accumulate stats1.
// grid = 1024 blocks x 8 tiles x 64 rows. 256 thr: 4-row x 4-out register tile.
// ---------------------------------------------------------------------------
__global__ __launch_bounds__(256) void p2_kernel(
    const float* __restrict__ xyz, const float* __restrict__ newxyz,
    const float* __restrict__ P0, const int* __restrict__ gidx,
    const float* __restrict__ w0, const float* __restrict__ w1,
    const float* __restrict__ sc0g, const float* __restrict__ sh0g,
    unsigned short* __restrict__ act1, float* __restrict__ partials1) {
  __shared__ float W1s[64][64];  // [c][o]
  __shared__ float Xs[64][64];   // [c][row]
  __shared__ float w0x[64], w0y[64], w0z[64], sc0[64], sh0[64];
  __shared__ float Sred[256][8];
  const int t = threadIdx.x;
  for (int idx = t; idx < 4096; idx += 256) {
    int c = idx >> 6, o = idx & 63;
    W1s[c][o] = w1[o * 64 + c];
  }
  if (t < 64) {
    w0x[t] = w0[t * 67 + 0];
    w0y[t] = w0[t * 67 + 1];
    w0z[t] = w0[t * 67 + 2];
    sc0[t] = sc0g[t];
    sh0[t] = sh0g[t];
  }
  __syncthreads();
  const int i = t >> 4, j = t & 15;
  const int rl = t >> 2, cq = t & 3;
  float ssum[4] = {}, ssq[4] = {};
  for (int tile = 0; tile < 8; ++tile) {
    const int rowbase = (blockIdx.x * 8 + tile) << 6;
    {
      int r = rowbase + rl;
      int b = r >> 15, s = (r >> 5) & 1023;
      int g = gidx[r];
      const float* Pt = xyz + ((size_t)b * 4096 + g) * 3;
      const float* Ct = newxyz + ((size_t)b * 1024 + s) * 3;
      float dx = Pt[0] - Ct[0], dy = Pt[1] - Ct[1], dz = Pt[2] - Ct[2];
      const float* p0r = P0 + ((size_t)b * 4096 + g) * 64 + cq * 16;
      const float4* p4 = (const float4*)p0r;
      float4 a0 = p4[0], a1 = p4[1], a2 = p4[2], a3 = p4[3];
      float pv[16] = {a0.x, a0.y, a0.z, a0.w, a1.x, a1.y, a1.z, a1.w,
                      a2.x, a2.y, a2.z, a2.w, a3.x, a3.y, a3.z, a3.w};
#pragma unroll
      for (int cc = 0; cc < 16; ++cc) {
        int c = cq * 16 + cc;
        float a = fmaf(w0x[c], dx, fmaf(w0y[c], dy, fmaf(w0z[c], dz, pv[cc])));
        Xs[c][rl] = fmaxf(0.f, fmaf(a, sc0[c], sh0[c]));
      }
    }
    __syncthreads();
    float acc[4][4] = {};
#pragma unroll 4
    for (int c = 0; c < 64; ++c) {
      float4 xv = *(const float4*)&Xs[c][4 * i];
      float4 wv = *(const float4*)&W1s[c][4 * j];
      float xr[4] = {xv.x, xv.y, xv.z, xv.w};
      float wr[4] = {wv.x, wv.y, wv.z, wv.w};
#pragma unroll
      for (int rr = 0; rr < 4; ++rr)
#pragma unroll
        for (int oi = 0; oi < 4; ++oi) acc[rr][oi] = fmaf(xr[rr], wr[oi], acc[rr][oi]);
    }
#pragma unroll
    for (int rr = 0; rr < 4; ++rr) {
      size_t r = (size_t)rowbase + 4 * i + rr;
      ushort4 pk;
      float y0 = acc[rr][0], y1 = acc[rr][1], y2 = acc[rr][2], y3 = acc[rr][3];
      ssum[0] += y0; ssq[0] = fmaf(y0, y0, ssq[0]);
      ssum[1] += y1; ssq[1] = fmaf(y1, y1, ssq[1]);
      ssum[2] += y2; ssq[2] = fmaf(y2, y2, ssq[2]);
      ssum[3] += y3; ssq[3] = fmaf(y3, y3, ssq[3]);
      pk.x = f2bf(y0); pk.y = f2bf(y1); pk.z = f2bf(y2); pk.w = f2bf(y3);
      *(ushort4*)(act1 + r * 64 + 4 * j) = pk;
    }
    __syncthreads();
  }
#pragma unroll
  for (int oi = 0; oi < 4; ++oi) { Sred[t][oi] = ssum[oi]; Sred[t][4 + oi] = ssq[oi]; }
  __syncthreads();
  if (t < 64) {
    int jj = t >> 2, oi = t & 3;
    float s1 = 0.f, s2 = 0.f;
#pragma unroll
    for (int ii = 0; ii < 16; ++ii) {
      s1 += Sred[ii * 16 + jj][oi];
      s2 += Sred[ii * 16 + jj][4 + oi];
    }
    partials1[(size_t)t * 1024 + blockIdx.x] = s1;
    partials1[(size_t)(64 + t) * 1024 + blockIdx.x] = s2;
  }
}

// ---------------------------------------------------------------------------
// P3: stats of act2_raw = W2 * relu(bn1(act1)) (no store; P4 recomputes).
// ---------------------------------------------------------------------------
__global__ __launch_bounds__(256) void p3_kernel(
    const unsigned short* __restrict__ act1, const float* __restrict__ w2,
    const float* __restrict__ sc1g, const float* __restrict__ sh1g,
    float* __restrict__ partials2) {
  __shared__ float W2s[64][128];  // [c][o]
  __shared__ union US { float Xs[64][64]; float Sred[256][16]; } u;
  __shared__ float sc1[64], sh1[64];
  const int t = threadIdx.x;
  for (int idx = t; idx < 8192; idx += 256) {
    int c = idx >> 7, o = idx & 127;
    W2s[c][o] = w2[o * 64 + c];
  }
  if (t < 64) { sc1[t] = sc1g[t]; sh1[t] = sh1g[t]; }
  __syncthreads();
  const int i = t >> 4, j = t & 15;
  const int rl = t >> 2, cq = t & 3;
  float ssum[8] = {}, ssq[8] = {};
  for (int tile = 0; tile < 8; ++tile) {
    const int rowbase = (blockIdx.x * 8 + tile) << 6;
    {
      size_t r = (size_t)rowbase + rl;
      const uint4* pr = (const uint4*)(act1 + r * 64 + cq * 16);
      uint4 aa = pr[0], bb = pr[1];
      unsigned int uu[8] = {aa.x, aa.y, aa.z, aa.w, bb.x, bb.y, bb.z, bb.w};
#pragma unroll
      for (int q = 0; q < 8; ++q) {
        int c = cq * 16 + 2 * q;
        float v0 = bf2f((unsigned short)(uu[q] & 0xffffu));
        float v1 = bf2f((unsigned short)(uu[q] >> 16));
        u.Xs[c][rl] = fmaxf(0.f, fmaf(v0, sc1[c], sh1[c]));
        u.Xs[c + 1][rl] = fmaxf(0.f, fmaf(v1, sc1[c + 1], sh1[c + 1]));
      }
    }
    __syncthreads();
    float acc[4][8] = {};
#pragma unroll 2
    for (int c = 0; c < 64; ++c) {
      float4 xv = *(const float4*)&u.Xs[c][4 * i];
      float4 wa = *(const float4*)&W2s[c][4 * j];
      float4 wb = *(const float4*)&W2s[c][64 + 4 * j];
      float xr[4] = {xv.x, xv.y, xv.z, xv.w};
      float wr[8] = {wa.x, wa.y, wa.z, wa.w, wb.x, wb.y, wb.z, wb.w};
#pragma unroll
      for (int rr = 0; rr < 4; ++rr)
#pragma unroll
        for (int q = 0; q < 8; ++q) acc[rr][q] = fmaf(xr[rr], wr[q], acc[rr][q]);
    }
#pragma unroll
    for (int rr = 0; rr < 4; ++rr)
#pragma unroll
      for (int q = 0; q < 8; ++q) {
        float y = acc[rr][q];
        ssum[q] += y;
        ssq[q] = fmaf(y, y, ssq[q]);
      }
    __syncthreads();
  }
#pragma unroll
  for (int q = 0; q < 8; ++q) { u.Sred[t][q] = ssum[q]; u.Sred[t][8 + q] = ssq[q]; }
  __syncthreads();
  if (t < 128) {
    int o = t;
    int jj = (o & 63) >> 2, oh = o >> 6, oi = o & 3, slot = oh * 4 + oi;
    float s1 = 0.f, s2 = 0.f;
#pragma unroll
    for (int ii = 0; ii < 16; ++ii) {
      s1 += u.Sred[ii * 16 + jj][slot];
      s2 += u.Sred[ii * 16 + jj][8 + slot];
    }
    partials2[(size_t)o * 1024 + blockIdx.x] = s1;
    partials2[(size_t)(128 + o) * 1024 + blockIdx.x] = s2;
  }
}

// ---------------------------------------------------------------------------
// P4: recompute act2, bn2+relu, max over K=32, write feats[b][o][s].
// grid = 8192 blocks, 1 tile = 64 rows = 2 groups each.
// ---------------------------------------------------------------------------
__global__ __launch_bounds__(256) void p4_kernel(
    const unsigned short* __restrict__ act1, const float* __restrict__ w2,
    const float* __restrict__ sc1g, const float* __restrict__ sh1g,
    const float* __restrict__ sc2g, const float* __restrict__ sh2g,
    float* __restrict__ feats) {
  __shared__ float W2s[64][128];
  __shared__ float Xs[64][64];
  __shared__ float Mred[16][132];  // padded stride vs 128 to dodge bank conflicts
  __shared__ float sc1[64], sh1[64], sc2[128], sh2[128];
  const int t = threadIdx.x;
  for (int idx = t; idx < 8192; idx += 256) {
    int c = idx >> 7, o = idx & 127;
    W2s[c][o] = w2[o * 64 + c];
  }
  if (t < 64) { sc1[t] = sc1g[t]; sh1[t] = sh1g[t]; }
  if (t < 128) { sc2[t] = sc2g[t]; sh2[t] = sh2g[t]; }
  __syncthreads();
  const int i = t >> 4, j = t & 15;
  const int rl = t >> 2, cq = t & 3;
  const int rowbase = blockIdx.x << 6;
  {
    size_t r = (size_t)rowbase + rl;
    const uint4* pr = (const uint4*)(act1 + r * 64 + cq * 16);
    uint4 aa = pr[0], bb = pr[1];
    unsigned int uu[8] = {aa.x, aa.y, aa.z, aa.w, bb.x, bb.y, bb.z, bb.w};
#pragma unroll
    for (int q = 0; q < 8; ++q) {
      int c = cq * 16 + 2 * q;
      float v0 = bf2f((unsigned short)(uu[q] & 0xffffu));
      float v1 = bf2f((unsigned short)(uu[q] >> 16));
      Xs[c][rl] = fmaxf(0.f, fmaf(v0, sc1[c], sh1[c]));
      Xs[c + 1][rl] = fmaxf(0.f, fmaf(v1, sc1[c + 1], sh1[c + 1]));
    }
  }
  __syncthreads();
  float acc[4][8] = {};
#pragma unroll 2
  for (int c = 0; c < 64; ++c) {
    float4 xv = *(const float4*)&Xs[c][4 * i];
    float4 wa = *(const float4*)&W2s[c][4 * j];
    float4 wb = *(const float4*)&W2s[c][64 + 4 * j];
    float xr[4] = {xv.x, xv.y, xv.z, xv.w};
    float wr[8] = {wa.x, wa.y, wa.z, wa.w, wb.x, wb.y, wb.z, wb.w};
#pragma unroll
    for (int rr = 0; rr < 4; ++rr)
#pragma unroll
      for (int q = 0; q < 8; ++q) acc[rr][q] = fmaf(xr[rr], wr[q], acc[rr][q]);
  }
  // rows 4i..4i+3 are all in group (i>>3); per-thread max over them.
#pragma unroll
  for (int q = 0; q < 8; ++q) {
    int oh = q >> 2, oi = q & 3;
    int o = 4 * j + 64 * oh + oi;
    float m = 0.f;  // relu output >= 0
#pragma unroll
    for (int rr = 0; rr < 4; ++rr) {
      float v = fmaxf(0.f, fmaf(acc[rr][q], sc2[o], sh2[o]));
      m = fmaxf(m, v);
    }
    Mred[i][o] = m;
  }
  __syncthreads();
  {
    int o = t & 127, g = t >> 7;
    float v = 0.f;
#pragma unroll
    for (int ii = 0; ii < 8; ++ii) v = fmaxf(v, Mred[g * 8 + ii][o]);
    int b = rowbase >> 15;
    int s = ((rowbase >> 5) & 1023) + g;
    feats[(size_t)b * 131072 + (size_t)o * 1024 + s] = v;
  }
}

// ---------------------------------------------------------------------------
extern "C" void kernel_launch(void* const* d_in, const int* in_sizes, int n_in,
                              void* d_out, int out_size, void* d_ws, size_t ws_size,
                              hipStream_t stream) {
  const float* xyz = (const float*)d_in[0];
  const float* points = (const float*)d_in[1];
  const float* w0 = (const float*)d_in[2];
  const float* g0 = (const float*)d_in[3];
  const float* b0 = (const float*)d_in[4];
  const float* w1 = (const float*)d_in[5];
  const float* g1 = (const float*)d_in[6];
  const float* b1 = (const float*)d_in[7];
  const float* w2 = (const float*)d_in[8];
  const float* g2 = (const float*)d_in[9];
  const float* b2 = (const float*)d_in[10];

  float* out = (float*)d_out;
  float* newxyz = out;            // (16,1024,3)
  float* feats = out + 49152;     // (16,128,1024)

  char* ws = (char*)d_ws;
  float* P0 = (float*)ws;                                        // 16 MB  [b][n][64]
  int* gidx = (int*)(ws + (size_t)(16u << 20));                  // 2 MB
  unsigned short* act1 = (unsigned short*)(ws + (size_t)(18u << 20));  // 64 MB bf16
  float* partials0 = (float*)(ws + (size_t)(82u << 20));         // 2 MB   [128][4096]
  float* partials1 = (float*)(ws + (size_t)(84u << 20));         // 0.5 MB [128][1024]
  float* partials2 = (float*)(ws + (size_t)(85u << 20));         // 1 MB   [256][1024]
  float* sc0 = (float*)(ws + (size_t)(86u << 20));               // 6*128 floats
  float* sh0 = sc0 + 128;
  float* sc1 = sc0 + 256;
  float* sh1 = sc0 + 384;
  float* sc2 = sc0 + 512;
  float* sh2 = sc0 + 640;

  fps_kernel<<<16, 256, 0, stream>>>(xyz, newxyz);
  p0_kernel<<<1024, 256, 0, stream>>>(points, w0, P0);
  ballquery_stats0_kernel<<<4096, 256, 0, stream>>>(xyz, newxyz, P0, w0, gidx, partials0);
  finalize_kernel<<<64, 256, 0, stream>>>(partials0, 64, 4096, g0, b0, sc0, sh0);
  p2_kernel<<<1024, 256, 0, stream>>>(xyz, newxyz, P0, gidx, w0, w1, sc0, sh0, act1, partials1);
  finalize_kernel<<<64, 256, 0, stream>>>(partials1, 64, 1024, g1, b1, sc1, sh1);
  p3_kernel<<<1024, 256, 0, stream>>>(act1, w2, sc1, sh1, partials2);
  finalize_kernel<<<128, 256, 0, stream>>>(partials2, 128, 1024, g2, b2, sc2, sh2);
  p4_kernel<<<8192, 256, 0, stream>>>(act1, w2, sc1, sh1, sc2, sh2, feats);
}

// Round 8
// 1009.989 us; speedup vs baseline: 1.4460x; 1.1594x over previous
//
#include <hip/hip_runtime.h>

#define DI static __device__ __forceinline__

typedef float v2f __attribute__((ext_vector_type(2)));

DI unsigned short f2bf(float f) {
  unsigned int u = __float_as_uint(f);
  u = (u + 0x7fffu + ((u >> 16) & 1u)) >> 16;
  return (unsigned short)u;
}
DI float bf2f(unsigned short h) { return __uint_as_float(((unsigned int)h) << 16); }

// DPP wave64 reduce steps (VALU pipe). update_dpp(old=v, src=v, ctrl, 0xf,
// 0xf, false): lanes with invalid source keep old=v (idempotent for max/min).
#define DPP_MAXU(v, ctrl)                                                      \
  {                                                                            \
    unsigned o_ = (unsigned)__builtin_amdgcn_update_dpp((int)(v), (int)(v),    \
                                                        (ctrl), 0xf, 0xf, false); \
    (v) = (o_ > (v)) ? o_ : (v);                                               \
  }
#define DPP_MINU(v, ctrl)                                                      \
  {                                                                            \
    unsigned o_ = (unsigned)__builtin_amdgcn_update_dpp((int)(v), (int)(v),    \
                                                        (ctrl), 0xf, 0xf, false); \
    (v) = (o_ < (v)) ? o_ : (v);                                               \
  }

// ---------------------------------------------------------------------------
// FPS: one block per batch, 256 threads (4 waves), 16 points/thread as 8 v2f.
// Distance arithmetic = exact rn sequence verified bit-exact in r3. Frozen
// since r7 (609 us, ~55% VALU-issue-bound on its 16 CUs).
// ---------------------------------------------------------------------------
__global__ __launch_bounds__(256) void fps_kernel(const float* __restrict__ xyz,
                                                  float* __restrict__ newxyz) {
  const int b = blockIdx.x;
  const int t = threadIdx.x;
  const int lane = t & 63, wid = t >> 6;  // 4 waves
  const float* X = xyz + (size_t)b * 4096 * 3;
  __shared__ float XL[4096 * 3];
  __shared__ int FI[1024];
  __shared__ unsigned long long slot[2][4];
  for (int idx = t; idx < 12288; idx += 256) XL[idx] = X[idx];
  v2f px[8], py[8], pz[8], dist[8];
#pragma unroll
  for (int q = 0; q < 8; ++q) {
    int i0 = t + (q << 9);  // t + 512q
    int i1 = i0 + 256;      // t + 512q + 256  (ascending with q)
    px[q] = (v2f){X[i0 * 3 + 0], X[i1 * 3 + 0]};
    py[q] = (v2f){X[i0 * 3 + 1], X[i1 * 3 + 1]};
    pz[q] = (v2f){X[i0 * 3 + 2], X[i1 * 3 + 2]};
    dist[q] = (v2f){3.402823466e38f, 3.402823466e38f};
  }
  __syncthreads();
  float cx = XL[0], cy = XL[1], cz = XL[2];  // farthest = 0 initially
  int fi = 0;
  for (int s = 0; s < 1024; ++s) {
    if (t == 0) FI[s] = fi;  // centroid index used this step (LDS, cheap)
    float bv = -1.0f;
    unsigned int bi = 0;
    v2f cxv = (v2f){cx, cx}, cyv = (v2f){cy, cy}, czv = (v2f){cz, cz};
#pragma unroll
    for (int q = 0; q < 8; ++q) {
#pragma clang fp contract(off)
      v2f dx = px[q] - cxv;
      v2f dy = py[q] - cyv;
      v2f dz = pz[q] - czv;
      v2f d = (dx * dx + dy * dy) + dz * dz;  // elementwise rn, no contraction
#if __has_builtin(__builtin_elementwise_min)
      v2f nd = __builtin_elementwise_min(dist[q], d);
#else
      v2f nd;
      nd.x = fminf(dist[q].x, d.x);
      nd.y = fminf(dist[q].y, d.y);
#endif
      dist[q] = nd;
      float n0 = nd.x, n1 = nd.y;
      // ascending index order within thread; strict > keeps earliest
      bool c0 = (n0 > bv);
      bv = c0 ? n0 : bv;
      bi = c0 ? (unsigned)(t + (q << 9)) : bi;
      bool c1 = (n1 > bv);
      bv = c1 ? n1 : bv;
      bi = c1 ? (unsigned)(t + (q << 9) + 256) : bi;
    }
    // ---- phase 1: wave max of dist bits (DPP, VALU-latency) ----
    unsigned vb = __float_as_uint(bv);  // bv >= 0 -> uint order == float order
    unsigned m = vb;
    DPP_MAXU(m, 0x111);  // row_shr:1
    DPP_MAXU(m, 0x112);  // row_shr:2
    DPP_MAXU(m, 0x114);  // row_shr:4
    DPP_MAXU(m, 0x118);  // row_shr:8
    DPP_MAXU(m, 0x142);  // row_bcast:15
    DPP_MAXU(m, 0x143);  // row_bcast:31
    unsigned wmax = (unsigned)__builtin_amdgcn_readlane((int)m, 63);
    // ---- phase 2: wave min index among lanes at the max ----
    unsigned ik = (vb == wmax) ? bi : 0xFFFFFFFFu;
    DPP_MINU(ik, 0x111);
    DPP_MINU(ik, 0x112);
    DPP_MINU(ik, 0x114);
    DPP_MINU(ik, 0x118);
    DPP_MINU(ik, 0x142);
    DPP_MINU(ik, 0x143);
    unsigned widx = (unsigned)__builtin_amdgcn_readlane((int)ik, 63);
    const int p = s & 1;
    if (lane == 0)
      slot[p][wid] = ((unsigned long long)wmax << 32) | (unsigned long long)(~widx);
    __syncthreads();
    // 4-way block winner: max key == max dist, tie -> min idx (bigger ~idx)
    unsigned long long k0 = slot[p][0], k1 = slot[p][1];
    unsigned long long k2 = slot[p][2], k3 = slot[p][3];
    unsigned long long m01 = (k0 >= k1) ? k0 : k1;
    unsigned long long m23 = (k2 >= k3) ? k2 : k3;
    unsigned long long win = (m01 >= m23) ? m01 : m23;
    fi = (int)(~(unsigned int)win);  // winner index in [0,4095]
    cx = XL[fi * 3 + 0];
    cy = XL[fi * 3 + 1];
    cz = XL[fi * 3 + 2];
  }
  __syncthreads();
  // batched centroid write-out (once per kernel)
  float* out = newxyz + (size_t)b * 1024 * 3;
  for (int s2 = t; s2 < 1024; s2 += 256) {
    int f = FI[s2];
    out[s2 * 3 + 0] = XL[f * 3 + 0];
    out[s2 * 3 + 1] = XL[f * 3 + 1];
    out[s2 * 3 + 2] = XL[f * 3 + 2];
  }
}

// ---------------------------------------------------------------------------
// P0[b][n][o] = sum_c W0[o][3+c] * points[b][c][n]   (pushes mm0 through gather)
// ---------------------------------------------------------------------------
__global__ __launch_bounds__(256) void p0_kernel(const float* __restrict__ points,
                                                 const float* __restrict__ w0,
                                                 float* __restrict__ P0) {
  const int b = blockIdx.x >> 6;
  const int n0 = (blockIdx.x & 63) << 6;
  const int t = threadIdx.x;
  __shared__ float W[64][64];  // [c][o]
  for (int idx = t; idx < 4096; idx += 256) {
    int c = idx >> 6, o = idx & 63;
    W[c][o] = w0[o * 67 + 3 + c];
  }
  __syncthreads();
  const int i = t >> 4, j = t & 15;
  const float* Pb = points + (size_t)b * 64 * 4096 + n0 + 4 * i;
  float acc[4][4] = {};
  for (int c = 0; c < 64; ++c) {
    float4 xv = *(const float4*)(Pb + (size_t)c * 4096);
    float4 wv = *(const float4*)&W[c][4 * j];
    float xr[4] = {xv.x, xv.y, xv.z, xv.w};
    float wr[4] = {wv.x, wv.y, wv.z, wv.w};
#pragma unroll
    for (int rr = 0; rr < 4; ++rr)
#pragma unroll
      for (int oi = 0; oi < 4; ++oi) acc[rr][oi] = fmaf(xr[rr], wr[oi], acc[rr][oi]);
  }
#pragma unroll
  for (int rr = 0; rr < 4; ++rr) {
    float4 vv = make_float4(acc[rr][0], acc[rr][1], acc[rr][2], acc[rr][3]);
    *(float4*)(P0 + ((size_t)b * 4096 + n0 + 4 * i + rr) * 64 + 4 * j) = vv;
  }
}

// ---------------------------------------------------------------------------
// Ball query fused with layer-0 stats (XLA-CPU fp32 emulation VERIFIED r3).
// ---------------------------------------------------------------------------
__global__ __launch_bounds__(256) void ballquery_stats0_kernel(
    const float* __restrict__ xyz, const float* __restrict__ newxyz,
    const float* __restrict__ P0, const float* __restrict__ w0,
    int* __restrict__ gidx, float* __restrict__ partials0) {
  const int t = threadIdx.x;
  const int lane = t & 63, w = t >> 6;
  const int gid = blockIdx.x * 4 + w;  // 0..16383
  const int b = gid >> 10;
  __shared__ int sel[4][32];
  __shared__ float red[4][128];
  const float* Xb = xyz + (size_t)b * 4096 * 3;
  const float cx = newxyz[(size_t)gid * 3 + 0];
  const float cy = newxyz[(size_t)gid * 3 + 1];
  const float cz = newxyz[(size_t)gid * 3 + 2];
  const float cs = __fadd_rn(__fadd_rn(__fmul_rn(cx, cx), __fmul_rn(cy, cy)), __fmul_rn(cz, cz));
  int cnt = 0, first = 0;
  bool found = false;
  for (int base = 0; base < 4096; base += 64) {
    int i = base + lane;
    float x = Xb[i * 3 + 0], y = Xb[i * 3 + 1], z = Xb[i * 3 + 2];
    float xs = __fadd_rn(__fadd_rn(__fmul_rn(x, x), __fmul_rn(y, y)), __fmul_rn(z, z));
    float dot = fmaf(cz, z, fmaf(cy, y, __fmul_rn(cx, x)));  // fma chain, d=0,1,2
    float sqr = __fsub_rn(__fadd_rn(cs, xs), __fmul_rn(2.0f, dot));
    bool ok = sqr <= 0.04f;
    unsigned long long mask = __ballot(ok);
    if (!found && mask != 0ull) { first = base + __builtin_ctzll(mask); found = true; }
    int pre = __popcll(mask & ((1ull << lane) - 1ull));
    int pos = cnt + pre;
    if (ok && pos < 32) sel[w][pos] = i;
    cnt += (int)__popcll(mask);
    if (cnt >= 32) break;
  }
  if (cnt < 32) {
    int pad = found ? first : 0;
    for (int p = cnt + lane; p < 32; p += 64) sel[w][p] = pad;
  }
  __syncthreads();
  if (lane < 32) gidx[(size_t)gid * 32 + lane] = sel[w][lane];
  const int c = lane;
  float wx = w0[c * 67 + 0], wy = w0[c * 67 + 1], wz = w0[c * 67 + 2];
  float ssum = 0.f, ssq = 0.f;
  const float* P0b = P0 + (size_t)b * 4096 * 64;
  for (int k = 0; k < 32; ++k) {
    int g = sel[w][k];
    float gx = Xb[g * 3 + 0] - cx, gy = Xb[g * 3 + 1] - cy, gz = Xb[g * 3 + 2] - cz;
    float a0 = fmaf(wx, gx, fmaf(wy, gy, fmaf(wz, gz, P0b[(size_t)g * 64 + c])));
    ssum += a0;
    ssq = fmaf(a0, a0, ssq);
  }
  red[w][c] = ssum;
  red[w][c + 64] = ssq;
  __syncthreads();
  if (t < 128) {
    float acc = red[0][t] + red[1][t] + red[2][t] + red[3][t];
    partials0[(size_t)t * 4096 + blockIdx.x] = acc;
  }
}

// ---------------------------------------------------------------------------
// finalize BN stats: scale = g*rsqrt(var+eps), shift = b - mean*scale
// ---------------------------------------------------------------------------
__global__ __launch_bounds__(256) void finalize_kernel(
    const float* __restrict__ partials, int C, int nblk,
    const float* __restrict__ gamma, const float* __restrict__ beta,
    float* __restrict__ scale, float* __restrict__ shift) {
  const int c = blockIdx.x, t = threadIdx.x;
  double s1 = 0.0, s2 = 0.0;
  for (int k = t; k < nblk; k += 256) {
    s1 += (double)partials[(size_t)c * nblk + k];
    s2 += (double)partials[(size_t)(C + c) * nblk + k];
  }
  __shared__ double r1[256], r2[256];
  r1[t] = s1;
  r2[t] = s2;
  __syncthreads();
  for (int off = 128; off > 0; off >>= 1) {
    if (t < off) { r1[t] += r1[t + off]; r2[t] += r2[t + off]; }
    __syncthreads();
  }
  if (t == 0) {
    const double M = 524288.0;
    double mean = r1[0] / M;
    double var = r2[0] / M - mean * mean;
    if (var < 0.0) var = 0.0;
    float sc = gamma[c] * (float)(1.0 / sqrt(var + 1e-5));
    scale[c] = sc;
    shift[c] = beta[c] - (float)mean * sc;
  }
}

// ---------------------------------------------------------------------------
// P2: act1_raw = W1 * relu(bn0(act0)), store bf16, accumulate stats1.
// ---------------------------------------------------------------------------
__global__ __launch_bounds__(256) void p2_kernel(
    const float* __restrict__ xyz, const float* __restrict__ newxyz,
    const float* __restrict__ P0, const int* __restrict__ gidx,
    const float* __restrict__ w0, const float* __restrict__ w1,
    const float* __restrict__ sc0g, const float* __restrict__ sh0g,
    unsigned short* __restrict__ act1, float* __restrict__ partials1) {
  __shared__ float W1s[64][64];  // [c][o]
  __shared__ float Xs[64][64];   // [c][row]
  __shared__ float w0x[64], w0y[64], w0z[64], sc0[64], sh0[64];
  __shared__ float Sred[256][8];
  const int t = threadIdx.x;
  for (int idx = t; idx < 4096; idx += 256) {
    int c = idx >> 6, o = idx & 63;
    W1s[c][o] = w1[o * 64 + c];
  }
  if (t < 64) {
    w0x[t] = w0[t * 67 + 0];
    w0y[t] = w0[t * 67 + 1];
    w0z[t] = w0[t * 67 + 2];
    sc0[t] = sc0g[t];
    sh0[t] = sh0g[t];
  }
  __syncthreads();
  const int i = t >> 4, j = t & 15;
  const int rl = t >> 2, cq = t & 3;
  float ssum[4] = {}, ssq[4] = {};
  for (int tile = 0; tile < 8; ++tile) {
    const int rowbase = (blockIdx.x * 8 + tile) << 6;
    {
      int r = rowbase + rl;
      int b = r >> 15, s = (r >> 5) & 1023;
      int g = gidx[r];
      const float* Pt = xyz + ((size_t)b * 4096 + g) * 3;
      const float* Ct = newxyz + ((size_t)b * 1024 + s) * 3;
      float dx = Pt[0] - Ct[0], dy = Pt[1] - Ct[1], dz = Pt[2] - Ct[2];
      const float* p0r = P0 + ((size_t)b * 4096 + g) * 64 + cq * 16;
      const float4* p4 = (const float4*)p0r;
      float4 a0 = p4[0], a1 = p4[1], a2 = p4[2], a3 = p4[3];
      float pv[16] = {a0.x, a0.y, a0.z, a0.w, a1.x, a1.y, a1.z, a1.w,
                      a2.x, a2.y, a2.z, a2.w, a3.x, a3.y, a3.z, a3.w};
#pragma unroll
      for (int cc = 0; cc < 16; ++cc) {
        int c = cq * 16 + cc;
        float a = fmaf(w0x[c], dx, fmaf(w0y[c], dy, fmaf(w0z[c], dz, pv[cc])));
        Xs[c][rl] = fmaxf(0.f, fmaf(a, sc0[c], sh0[c]));
      }
    }
    __syncthreads();
    float acc[4][4] = {};
#pragma unroll 4
    for (int c = 0; c < 64; ++c) {
      float4 xv = *(const float4*)&Xs[c][4 * i];
      float4 wv = *(const float4*)&W1s[c][4 * j];
      float xr[4] = {xv.x, xv.y, xv.z, xv.w};
      float wr[4] = {wv.x, wv.y, wv.z, wv.w};
#pragma unroll
      for (int rr = 0; rr < 4; ++rr)
#pragma unroll
        for (int oi = 0; oi < 4; ++oi) acc[rr][oi] = fmaf(xr[rr], wr[oi], acc[rr][oi]);
    }
#pragma unroll
    for (int rr = 0; rr < 4; ++rr) {
      size_t r = (size_t)rowbase + 4 * i + rr;
      ushort4 pk;
      float y0 = acc[rr][0], y1 = acc[rr][1], y2 = acc[rr][2], y3 = acc[rr][3];
      ssum[0] += y0; ssq[0] = fmaf(y0, y0, ssq[0]);
      ssum[1] += y1; ssq[1] = fmaf(y1, y1, ssq[1]);
      ssum[2] += y2; ssq[2] = fmaf(y2, y2, ssq[2]);
      ssum[3] += y3; ssq[3] = fmaf(y3, y3, ssq[3]);
      pk.x = f2bf(y0); pk.y = f2bf(y1); pk.z = f2bf(y2); pk.w = f2bf(y3);
      *(ushort4*)(act1 + r * 64 + 4 * j) = pk;
    }
    __syncthreads();
  }
#pragma unroll
  for (int oi = 0; oi < 4; ++oi) { Sred[t][oi] = ssum[oi]; Sred[t][4 + oi] = ssq[oi]; }
  __syncthreads();
  if (t < 64) {
    int jj = t >> 2, oi = t & 3;
    float s1 = 0.f, s2 = 0.f;
#pragma unroll
    for (int ii = 0; ii < 16; ++ii) {
      s1 += Sred[ii * 16 + jj][oi];
      s2 += Sred[ii * 16 + jj][4 + oi];
    }
    partials1[(size_t)t * 1024 + blockIdx.x] = s1;
    partials1[(size_t)(64 + t) * 1024 + blockIdx.x] = s2;
  }
}

// ---------------------------------------------------------------------------
// P3: act2_raw = W2 * relu(bn1(act1)); accumulates BN2 stats AND per-group
// (K=32) max/min of raw act2 per channel -> gmx/gmn [b][o][s] (o-major).
// This makes p4's GEMM recompute unnecessary: max_k relu(sc*x+sh) =
// relu(sc*mx+sh) if sc>=0 else relu(sc*mn+sh) — selection exact, final op
// identical per element -> bit-exact vs reference order.
// ---------------------------------------------------------------------------
__global__ __launch_bounds__(256) void p3_kernel(
    const unsigned short* __restrict__ act1, const float* __restrict__ w2,
    const float* __restrict__ sc1g, const float* __restrict__ sh1g,
    float* __restrict__ partials2, float* __restrict__ gmx,
    float* __restrict__ gmn) {
  __shared__ float W2s[64][128];  // [c][o]
  __shared__ union US { float Xs[64][64]; float Sred[256][16]; } u;
  __shared__ float Mred[16][132];  // +4 pad vs 128 (bank offset)
  __shared__ float Nred[16][132];
  __shared__ float sc1[64], sh1[64];
  const int t = threadIdx.x;
  for (int idx = t; idx < 8192; idx += 256) {
    int c = idx >> 7, o = idx & 127;
    W2s[c][o] = w2[o * 64 + c];
  }
  if (t < 64) { sc1[t] = sc1g[t]; sh1[t] = sh1g[t]; }
  __syncthreads();
  const int i = t >> 4, j = t & 15;
  const int rl = t >> 2, cq = t & 3;
  float ssum[8] = {}, ssq[8] = {};
  for (int tile = 0; tile < 8; ++tile) {
    const int rowbase = (blockIdx.x * 8 + tile) << 6;
    {
      size_t r = (size_t)rowbase + rl;
      const uint4* pr = (const uint4*)(act1 + r * 64 + cq * 16);
      uint4 aa = pr[0], bb = pr[1];
      unsigned int uu[8] = {aa.x, aa.y, aa.z, aa.w, bb.x, bb.y, bb.z, bb.w};
#pragma unroll
      for (int q = 0; q < 8; ++q) {
        int c = cq * 16 + 2 * q;
        float v0 = bf2f((unsigned short)(uu[q] & 0xffffu));
        float v1 = bf2f((unsigned short)(uu[q] >> 16));
        u.Xs[c][rl] = fmaxf(0.f, fmaf(v0, sc1[c], sh1[c]));
        u.Xs[c + 1][rl] = fmaxf(0.f, fmaf(v1, sc1[c + 1], sh1[c + 1]));
      }
    }
    __syncthreads();  // S1: Xs visible
    float acc[4][8] = {};
#pragma unroll 2
    for (int c = 0; c < 64; ++c) {
      float4 xv = *(const float4*)&u.Xs[c][4 * i];
      float4 wa = *(const float4*)&W2s[c][4 * j];
      float4 wb = *(const float4*)&W2s[c][64 + 4 * j];
      float xr[4] = {xv.x, xv.y, xv.z, xv.w};
      float wr[8] = {wa.x, wa.y, wa.z, wa.w, wb.x, wb.y, wb.z, wb.w};
#pragma unroll
      for (int rr = 0; rr < 4; ++rr)
#pragma unroll
        for (int q = 0; q < 8; ++q) acc[rr][q] = fmaf(xr[rr], wr[q], acc[rr][q]);
    }
    // stats + per-thread (4 rows, same group) max/min per output channel
#pragma unroll
    for (int q = 0; q < 8; ++q) {
      float y0 = acc[0][q], y1 = acc[1][q], y2 = acc[2][q], y3 = acc[3][q];
      ssum[q] += ((y0 + y1) + (y2 + y3));
      ssq[q] = fmaf(y0, y0, ssq[q]);
      ssq[q] = fmaf(y1, y1, ssq[q]);
      ssq[q] = fmaf(y2, y2, ssq[q]);
      ssq[q] = fmaf(y3, y3, ssq[q]);
      float mx = fmaxf(fmaxf(y0, y1), fmaxf(y2, y3));
      float mn = fminf(fminf(y0, y1), fminf(y2, y3));
      int o = 4 * j + ((q >> 2) << 6) + (q & 3);
      Mred[i][o] = mx;
      Nred[i][o] = mn;
    }
    __syncthreads();  // S2: Mred/Nred visible; GEMM done -> Xs free
    {
      int o = t & 127, g = t >> 7;  // 2 groups of 32 rows in this tile
      float mx = Mred[g * 8 + 0][o], mn = Nred[g * 8 + 0][o];
#pragma unroll
      for (int ii = 1; ii < 8; ++ii) {
        mx = fmaxf(mx, Mred[g * 8 + ii][o]);
        mn = fminf(mn, Nred[g * 8 + ii][o]);
      }
      int bb2 = rowbase >> 15;
      int ss2 = ((rowbase >> 5) & 1023) + g;
      size_t oidx = ((size_t)bb2 * 128 + o) * 1024 + ss2;
      gmx[oidx] = mx;
      gmn[oidx] = mn;
    }
    __syncthreads();  // S3: Mred/Nred reads done -> reusable next tile
  }
#pragma unroll
  for (int q = 0; q < 8; ++q) { u.Sred[t][q] = ssum[q]; u.Sred[t][8 + q] = ssq[q]; }
  __syncthreads();
  if (t < 128) {
    int o = t;
    int jj = (o & 63) >> 2, oh = o >> 6, oi = o & 3, slot = oh * 4 + oi;
    float s1 = 0.f, s2 = 0.f;
#pragma unroll
    for (int ii = 0; ii < 16; ++ii) {
      s1 += u.Sred[ii * 16 + jj][slot];
      s2 += u.Sred[ii * 16 + jj][8 + slot];
    }
    partials2[(size_t)o * 1024 + blockIdx.x] = s1;
    partials2[(size_t)(128 + o) * 1024 + blockIdx.x] = s2;
  }
}

// ---------------------------------------------------------------------------
// P4f: feats[b][o][s] = relu(sc2[o] * (sc2>=0 ? gmx : gmn) + sh2[o]).
// Pure elementwise: 24 MB traffic, memory-bound (~10 us).
// grid = 8192: bo = blk>>2 (0..2047), s = (blk&3)*256 + t.
// ---------------------------------------------------------------------------
__global__ __launch_bounds__(256) void p4f_kernel(
    const float* __restrict__ gmx, const float* __restrict__ gmn,
    const float* __restrict__ sc2g, const float* __restrict__ sh2g,
    float* __restrict__ feats) {
  const int bo = blockIdx.x >> 2;
  const int s = ((blockIdx.x & 3) << 8) + threadIdx.x;
  const int o = bo & 127;
  const float sc = sc2g[o], sh = sh2g[o];
  size_t idx = (size_t)bo * 1024 + s;
  float v = (sc >= 0.f) ? gmx[idx] : gmn[idx];
  feats[idx] = fmaxf(0.f, fmaf(v, sc, sh));
}

// ---------------------------------------------------------------------------
extern "C" void kernel_launch(void* const* d_in, const int* in_sizes, int n_in,
                              void* d_out, int out_size, void* d_ws, size_t ws_size,
                              hipStream_t stream) {
  const float* xyz = (const float*)d_in[0];
  const float* points = (const float*)d_in[1];
  const float* w0 = (const float*)d_in[2];
  const float* g0 = (const float*)d_in[3];
  const float* b0 = (const float*)d_in[4];
  const float* w1 = (const float*)d_in[5];
  const float* g1 = (const float*)d_in[6];
  const float* b1 = (const float*)d_in[7];
  const float* w2 = (const float*)d_in[8];
  const float* g2 = (const float*)d_in[9];
  const float* b2 = (const float*)d_in[10];

  float* out = (float*)d_out;
  float* newxyz = out;            // (16,1024,3)
  float* feats = out + 49152;     // (16,128,1024)

  char* ws = (char*)d_ws;
  float* P0 = (float*)ws;                                        // 16 MB  [b][n][64]
  // gmx/gmn reuse the P0 region: P0's last consumer is p2; p3 writes these.
  float* gmx = (float*)ws;                                       // 8 MB [b][o][s]
  float* gmn = (float*)(ws + (size_t)(8u << 20));                // 8 MB
  int* gidx = (int*)(ws + (size_t)(16u << 20));                  // 2 MB
  unsigned short* act1 = (unsigned short*)(ws + (size_t)(18u << 20));  // 64 MB bf16
  float* partials0 = (float*)(ws + (size_t)(82u << 20));         // 2 MB   [128][4096]
  float* partials1 = (float*)(ws + (size_t)(84u << 20));         // 0.5 MB [128][1024]
  float* partials2 = (float*)(ws + (size_t)(85u << 20));         // 1 MB   [256][1024]
  float* sc0 = (float*)(ws + (size_t)(86u << 20));               // 6*128 floats
  float* sh0 = sc0 + 128;
  float* sc1 = sc0 + 256;
  float* sh1 = sc0 + 384;
  float* sc2 = sc0 + 512;
  float* sh2 = sc0 + 640;

  fps_kernel<<<16, 256, 0, stream>>>(xyz, newxyz);
  p0_kernel<<<1024, 256, 0, stream>>>(points, w0, P0);
  ballquery_stats0_kernel<<<4096, 256, 0, stream>>>(xyz, newxyz, P0, w0, gidx, partials0);
  finalize_kernel<<<64, 256, 0, stream>>>(partials0, 64, 4096, g0, b0, sc0, sh0);
  p2_kernel<<<1024, 256, 0, stream>>>(xyz, newxyz, P0, gidx, w0, w1, sc0, sh0, act1, partials1);
  finalize_kernel<<<64, 256, 0, stream>>>(partials1, 64, 1024, g1, b1, sc1, sh1);
  p3_kernel<<<1024, 256, 0, stream>>>(act1, w2, sc1, sh1, partials2, gmx, gmn);
  finalize_kernel<<<128, 256, 0, stream>>>(partials2, 128, 1024, g2, b2, sc2, sh2);
  p4f_kernel<<<8192, 256, 0, stream>>>(gmx, gmn, sc2, sh2, feats);
}

// Round 9
// 921.980 us; speedup vs baseline: 1.5840x; 1.0955x over previous
//
#include <hip/hip_runtime.h>

#define DI static __device__ __forceinline__

typedef float v2f __attribute__((ext_vector_type(2)));
typedef __attribute__((ext_vector_type(8))) short bf16x8;
typedef __attribute__((ext_vector_type(4))) float f32x4;

DI unsigned short f2bf(float f) {
  unsigned int u = __float_as_uint(f);
  u = (u + 0x7fffu + ((u >> 16) & 1u)) >> 16;
  return (unsigned short)u;
}
DI float bf2f(unsigned short h) { return __uint_as_float(((unsigned int)h) << 16); }

// DPP wave64 reduce steps (VALU pipe). update_dpp(old=v, src=v, ctrl, 0xf,
// 0xf, false): lanes with invalid source keep old=v (idempotent for max/min).
#define DPP_MAXU(v, ctrl)                                                      \
  {                                                                            \
    unsigned o_ = (unsigned)__builtin_amdgcn_update_dpp((int)(v), (int)(v),    \
                                                        (ctrl), 0xf, 0xf, false); \
    (v) = (o_ > (v)) ? o_ : (v);                                               \
  }
#define DPP_MINU(v, ctrl)                                                      \
  {                                                                            \
    unsigned o_ = (unsigned)__builtin_amdgcn_update_dpp((int)(v), (int)(v),    \
                                                        (ctrl), 0xf, 0xf, false); \
    (v) = (o_ < (v)) ? o_ : (v);                                               \
  }

// ---------------------------------------------------------------------------
// FPS: frozen since r7 (609 us; ~55% VALU-issue-bound on its 16 CUs).
// Distance arithmetic = exact rn sequence verified bit-exact in r3.
// ---------------------------------------------------------------------------
__global__ __launch_bounds__(256) void fps_kernel(const float* __restrict__ xyz,
                                                  float* __restrict__ newxyz) {
  const int b = blockIdx.x;
  const int t = threadIdx.x;
  const int lane = t & 63, wid = t >> 6;  // 4 waves
  const float* X = xyz + (size_t)b * 4096 * 3;
  __shared__ float XL[4096 * 3];
  __shared__ int FI[1024];
  __shared__ unsigned long long slot[2][4];
  for (int idx = t; idx < 12288; idx += 256) XL[idx] = X[idx];
  v2f px[8], py[8], pz[8], dist[8];
#pragma unroll
  for (int q = 0; q < 8; ++q) {
    int i0 = t + (q << 9);  // t + 512q
    int i1 = i0 + 256;      // t + 512q + 256  (ascending with q)
    px[q] = (v2f){X[i0 * 3 + 0], X[i1 * 3 + 0]};
    py[q] = (v2f){X[i0 * 3 + 1], X[i1 * 3 + 1]};
    pz[q] = (v2f){X[i0 * 3 + 2], X[i1 * 3 + 2]};
    dist[q] = (v2f){3.402823466e38f, 3.402823466e38f};
  }
  __syncthreads();
  float cx = XL[0], cy = XL[1], cz = XL[2];  // farthest = 0 initially
  int fi = 0;
  for (int s = 0; s < 1024; ++s) {
    if (t == 0) FI[s] = fi;
    float bv = -1.0f;
    unsigned int bi = 0;
    v2f cxv = (v2f){cx, cx}, cyv = (v2f){cy, cy}, czv = (v2f){cz, cz};
#pragma unroll
    for (int q = 0; q < 8; ++q) {
#pragma clang fp contract(off)
      v2f dx = px[q] - cxv;
      v2f dy = py[q] - cyv;
      v2f dz = pz[q] - czv;
      v2f d = (dx * dx + dy * dy) + dz * dz;  // elementwise rn, no contraction
#if __has_builtin(__builtin_elementwise_min)
      v2f nd = __builtin_elementwise_min(dist[q], d);
#else
      v2f nd;
      nd.x = fminf(dist[q].x, d.x);
      nd.y = fminf(dist[q].y, d.y);
#endif
      dist[q] = nd;
      float n0 = nd.x, n1 = nd.y;
      bool c0 = (n0 > bv);
      bv = c0 ? n0 : bv;
      bi = c0 ? (unsigned)(t + (q << 9)) : bi;
      bool c1 = (n1 > bv);
      bv = c1 ? n1 : bv;
      bi = c1 ? (unsigned)(t + (q << 9) + 256) : bi;
    }
    unsigned vb = __float_as_uint(bv);
    unsigned m = vb;
    DPP_MAXU(m, 0x111);
    DPP_MAXU(m, 0x112);
    DPP_MAXU(m, 0x114);
    DPP_MAXU(m, 0x118);
    DPP_MAXU(m, 0x142);
    DPP_MAXU(m, 0x143);
    unsigned wmax = (unsigned)__builtin_amdgcn_readlane((int)m, 63);
    unsigned ik = (vb == wmax) ? bi : 0xFFFFFFFFu;
    DPP_MINU(ik, 0x111);
    DPP_MINU(ik, 0x112);
    DPP_MINU(ik, 0x114);
    DPP_MINU(ik, 0x118);
    DPP_MINU(ik, 0x142);
    DPP_MINU(ik, 0x143);
    unsigned widx = (unsigned)__builtin_amdgcn_readlane((int)ik, 63);
    const int p = s & 1;
    if (lane == 0)
      slot[p][wid] = ((unsigned long long)wmax << 32) | (unsigned long long)(~widx);
    __syncthreads();
    unsigned long long k0 = slot[p][0], k1 = slot[p][1];
    unsigned long long k2 = slot[p][2], k3 = slot[p][3];
    unsigned long long m01 = (k0 >= k1) ? k0 : k1;
    unsigned long long m23 = (k2 >= k3) ? k2 : k3;
    unsigned long long win = (m01 >= m23) ? m01 : m23;
    fi = (int)(~(unsigned int)win);
    cx = XL[fi * 3 + 0];
    cy = XL[fi * 3 + 1];
    cz = XL[fi * 3 + 2];
  }
  __syncthreads();
  float* out = newxyz + (size_t)b * 1024 * 3;
  for (int s2 = t; s2 < 1024; s2 += 256) {
    int f = FI[s2];
    out[s2 * 3 + 0] = XL[f * 3 + 0];
    out[s2 * 3 + 1] = XL[f * 3 + 1];
    out[s2 * 3 + 2] = XL[f * 3 + 2];
  }
}

// ---------------------------------------------------------------------------
// P0[b][n][o] = sum_c W0[o][3+c] * points[b][c][n]
// ---------------------------------------------------------------------------
__global__ __launch_bounds__(256) void p0_kernel(const float* __restrict__ points,
                                                 const float* __restrict__ w0,
                                                 float* __restrict__ P0) {
  const int b = blockIdx.x >> 6;
  const int n0 = (blockIdx.x & 63) << 6;
  const int t = threadIdx.x;
  __shared__ float W[64][64];  // [c][o]
  for (int idx = t; idx < 4096; idx += 256) {
    int c = idx >> 6, o = idx & 63;
    W[c][o] = w0[o * 67 + 3 + c];
  }
  __syncthreads();
  const int i = t >> 4, j = t & 15;
  const float* Pb = points + (size_t)b * 64 * 4096 + n0 + 4 * i;
  float acc[4][4] = {};
  for (int c = 0; c < 64; ++c) {
    float4 xv = *(const float4*)(Pb + (size_t)c * 4096);
    float4 wv = *(const float4*)&W[c][4 * j];
    float xr[4] = {xv.x, xv.y, xv.z, xv.w};
    float wr[4] = {wv.x, wv.y, wv.z, wv.w};
#pragma unroll
    for (int rr = 0; rr < 4; ++rr)
#pragma unroll
      for (int oi = 0; oi < 4; ++oi) acc[rr][oi] = fmaf(xr[rr], wr[oi], acc[rr][oi]);
  }
#pragma unroll
  for (int rr = 0; rr < 4; ++rr) {
    float4 vv = make_float4(acc[rr][0], acc[rr][1], acc[rr][2], acc[rr][3]);
    *(float4*)(P0 + ((size_t)b * 4096 + n0 + 4 * i + rr) * 64 + 4 * j) = vv;
  }
}

// ---------------------------------------------------------------------------
// Ball query fused with layer-0 stats (XLA-CPU fp32 emulation VERIFIED r3).
// ---------------------------------------------------------------------------
__global__ __launch_bounds__(256) void ballquery_stats0_kernel(
    const float* __restrict__ xyz, const float* __restrict__ newxyz,
    const float* __restrict__ P0, const float* __restrict__ w0,
    int* __restrict__ gidx, float* __restrict__ partials0) {
  const int t = threadIdx.x;
  const int lane = t & 63, w = t >> 6;
  const int gid = blockIdx.x * 4 + w;  // 0..16383
  const int b = gid >> 10;
  __shared__ int sel[4][32];
  __shared__ float red[4][128];
  const float* Xb = xyz + (size_t)b * 4096 * 3;
  const float cx = newxyz[(size_t)gid * 3 + 0];
  const float cy = newxyz[(size_t)gid * 3 + 1];
  const float cz = newxyz[(size_t)gid * 3 + 2];
  const float cs = __fadd_rn(__fadd_rn(__fmul_rn(cx, cx), __fmul_rn(cy, cy)), __fmul_rn(cz, cz));
  int cnt = 0, first = 0;
  bool found = false;
  for (int base = 0; base < 4096; base += 64) {
    int i = base + lane;
    float x = Xb[i * 3 + 0], y = Xb[i * 3 + 1], z = Xb[i * 3 + 2];
    float xs = __fadd_rn(__fadd_rn(__fmul_rn(x, x), __fmul_rn(y, y)), __fmul_rn(z, z));
    float dot = fmaf(cz, z, fmaf(cy, y, __fmul_rn(cx, x)));  // fma chain, d=0,1,2
    float sqr = __fsub_rn(__fadd_rn(cs, xs), __fmul_rn(2.0f, dot));
    bool ok = sqr <= 0.04f;
    unsigned long long mask = __ballot(ok);
    if (!found && mask != 0ull) { first = base + __builtin_ctzll(mask); found = true; }
    int pre = __popcll(mask & ((1ull << lane) - 1ull));
    int pos = cnt + pre;
    if (ok && pos < 32) sel[w][pos] = i;
    cnt += (int)__popcll(mask);
    if (cnt >= 32) break;
  }
  if (cnt < 32) {
    int pad = found ? first : 0;
    for (int p = cnt + lane; p < 32; p += 64) sel[w][p] = pad;
  }
  __syncthreads();
  if (lane < 32) gidx[(size_t)gid * 32 + lane] = sel[w][lane];
  const int c = lane;
  float wx = w0[c * 67 + 0], wy = w0[c * 67 + 1], wz = w0[c * 67 + 2];
  float ssum = 0.f, ssq = 0.f;
  const float* P0b = P0 + (size_t)b * 4096 * 64;
  for (int k = 0; k < 32; ++k) {
    int g = sel[w][k];
    float gx = Xb[g * 3 + 0] - cx, gy = Xb[g * 3 + 1] - cy, gz = Xb[g * 3 + 2] - cz;
    float a0 = fmaf(wx, gx, fmaf(wy, gy, fmaf(wz, gz, P0b[(size_t)g * 64 + c])));
    ssum += a0;
    ssq = fmaf(a0, a0, ssq);
  }
  red[w][c] = ssum;
  red[w][c + 64] = ssq;
  __syncthreads();
  if (t < 128) {
    float acc = red[0][t] + red[1][t] + red[2][t] + red[3][t];
    partials0[(size_t)t * 4096 + blockIdx.x] = acc;
  }
}

// ---------------------------------------------------------------------------
// finalize BN stats: scale = g*rsqrt(var+eps), shift = b - mean*scale
// ---------------------------------------------------------------------------
__global__ __launch_bounds__(256) void finalize_kernel(
    const float* __restrict__ partials, int C, int nblk,
    const float* __restrict__ gamma, const float* __restrict__ beta,
    float* __restrict__ scale, float* __restrict__ shift) {
  const int c = blockIdx.x, t = threadIdx.x;
  double s1 = 0.0, s2 = 0.0;
  for (int k = t; k < nblk; k += 256) {
    s1 += (double)partials[(size_t)c * nblk + k];
    s2 += (double)partials[(size_t)(C + c) * nblk + k];
  }
  __shared__ double r1[256], r2[256];
  r1[t] = s1;
  r2[t] = s2;
  __syncthreads();
  for (int off = 128; off > 0; off >>= 1) {
    if (t < off) { r1[t] += r1[t + off]; r2[t] += r2[t + off]; }
    __syncthreads();
  }
  if (t == 0) {
    const double M = 524288.0;
    double mean = r1[0] / M;
    double var = r2[0] / M - mean * mean;
    if (var < 0.0) var = 0.0;
    float sc = gamma[c] * (float)(1.0 / sqrt(var + 1e-5));
    scale[c] = sc;
    shift[c] = beta[c] - (float)mean * sc;
  }
}

// ---------------------------------------------------------------------------
// P2: act1_raw = W1 * relu(bn0(act0)), store bf16, accumulate stats1.
// ---------------------------------------------------------------------------
__global__ __launch_bounds__(256) void p2_kernel(
    const float* __restrict__ xyz, const float* __restrict__ newxyz,
    const float* __restrict__ P0, const int* __restrict__ gidx,
    const float* __restrict__ w0, const float* __restrict__ w1,
    const float* __restrict__ sc0g, const float* __restrict__ sh0g,
    unsigned short* __restrict__ act1, float* __restrict__ partials1) {
  __shared__ float W1s[64][64];  // [c][o]
  __shared__ float Xs[64][64];   // [c][row]
  __shared__ float w0x[64], w0y[64], w0z[64], sc0[64], sh0[64];
  __shared__ float Sred[256][8];
  const int t = threadIdx.x;
  for (int idx = t; idx < 4096; idx += 256) {
    int c = idx >> 6, o = idx & 63;
    W1s[c][o] = w1[o * 64 + c];
  }
  if (t < 64) {
    w0x[t] = w0[t * 67 + 0];
    w0y[t] = w0[t * 67 + 1];
    w0z[t] = w0[t * 67 + 2];
    sc0[t] = sc0g[t];
    sh0[t] = sh0g[t];
  }
  __syncthreads();
  const int i = t >> 4, j = t & 15;
  const int rl = t >> 2, cq = t & 3;
  float ssum[4] = {}, ssq[4] = {};
  for (int tile = 0; tile < 8; ++tile) {
    const int rowbase = (blockIdx.x * 8 + tile) << 6;
    {
      int r = rowbase + rl;
      int b = r >> 15, s = (r >> 5) & 1023;
      int g = gidx[r];
      const float* Pt = xyz + ((size_t)b * 4096 + g) * 3;
      const float* Ct = newxyz + ((size_t)b * 1024 + s) * 3;
      float dx = Pt[0] - Ct[0], dy = Pt[1] - Ct[1], dz = Pt[2] - Ct[2];
      const float* p0r = P0 + ((size_t)b * 4096 + g) * 64 + cq * 16;
      const float4* p4 = (const float4*)p0r;
      float4 a0 = p4[0], a1 = p4[1], a2 = p4[2], a3 = p4[3];
      float pv[16] = {a0.x, a0.y, a0.z, a0.w, a1.x, a1.y, a1.z, a1.w,
                      a2.x, a2.y, a2.z, a2.w, a3.x, a3.y, a3.z, a3.w};
#pragma unroll
      for (int cc = 0; cc < 16; ++cc) {
        int c = cq * 16 + cc;
        float a = fmaf(w0x[c], dx, fmaf(w0y[c], dy, fmaf(w0z[c], dz, pv[cc])));
        Xs[c][rl] = fmaxf(0.f, fmaf(a, sc0[c], sh0[c]));
      }
    }
    __syncthreads();
    float acc[4][4] = {};
#pragma unroll 4
    for (int c = 0; c < 64; ++c) {
      float4 xv = *(const float4*)&Xs[c][4 * i];
      float4 wv = *(const float4*)&W1s[c][4 * j];
      float xr[4] = {xv.x, xv.y, xv.z, xv.w};
      float wr[4] = {wv.x, wv.y, wv.z, wv.w};
#pragma unroll
      for (int rr = 0; rr < 4; ++rr)
#pragma unroll
        for (int oi = 0; oi < 4; ++oi) acc[rr][oi] = fmaf(xr[rr], wr[oi], acc[rr][oi]);
    }
#pragma unroll
    for (int rr = 0; rr < 4; ++rr) {
      size_t r = (size_t)rowbase + 4 * i + rr;
      ushort4 pk;
      float y0 = acc[rr][0], y1 = acc[rr][1], y2 = acc[rr][2], y3 = acc[rr][3];
      ssum[0] += y0; ssq[0] = fmaf(y0, y0, ssq[0]);
      ssum[1] += y1; ssq[1] = fmaf(y1, y1, ssq[1]);
      ssum[2] += y2; ssq[2] = fmaf(y2, y2, ssq[2]);
      ssum[3] += y3; ssq[3] = fmaf(y3, y3, ssq[3]);
      pk.x = f2bf(y0); pk.y = f2bf(y1); pk.z = f2bf(y2); pk.w = f2bf(y3);
      *(ushort4*)(act1 + r * 64 + 4 * j) = pk;
    }
    __syncthreads();
  }
#pragma unroll
  for (int oi = 0; oi < 4; ++oi) { Sred[t][oi] = ssum[oi]; Sred[t][4 + oi] = ssq[oi]; }
  __syncthreads();
  if (t < 64) {
    int jj = t >> 2, oi = t & 3;
    float s1 = 0.f, s2 = 0.f;
#pragma unroll
    for (int ii = 0; ii < 16; ++ii) {
      s1 += Sred[ii * 16 + jj][oi];
      s2 += Sred[ii * 16 + jj][4 + oi];
    }
    partials1[(size_t)t * 1024 + blockIdx.x] = s1;
    partials1[(size_t)(64 + t) * 1024 + blockIdx.x] = s2;
  }
}

// ---------------------------------------------------------------------------
// P3 (MFMA): act2_raw = W2 * relu(bn1(act1)) via bf16 mfma_f32_16x16x32.
// A = bf16(relu(bn1(act1))) [64 x 72pad], B = bf16(w2) as [o][c] [128 x 72pad].
// Wave w computes rows w*16..+15 x 128 cols: 8 n-tiles x 2 K-steps = 16 MFMA.
// C/D layout: col = lane&15, row = (lane>>4)*4 + reg  [m89 verified].
// Stats + per-group(K=32) max/min of raw act2 -> partials2, gmx/gmn.
// ---------------------------------------------------------------------------
__global__ __launch_bounds__(256) void p3_kernel(
    const unsigned short* __restrict__ act1, const float* __restrict__ w2,
    const float* __restrict__ sc1g, const float* __restrict__ sh1g,
    float* __restrict__ partials2, float* __restrict__ gmx,
    float* __restrict__ gmn) {
  __shared__ unsigned short W2T[128 * 72];  // [o][c] bf16, pad 72
  __shared__ unsigned short A[64 * 72];     // [r][k] bf16, pad 72
  __shared__ float Mred[4][132], Nred[4][132];
  __shared__ float S1r[4][132], S2r[4][132];
  __shared__ float sc1[64], sh1[64];
  const int t = threadIdx.x;
  const int lane = t & 63, w = t >> 6;
  const int quad = lane >> 4, l15 = lane & 15;
  for (int idx = t; idx < 8192; idx += 256) {
    int o = idx >> 6, c = idx & 63;
    W2T[o * 72 + c] = f2bf(w2[o * 64 + c]);
  }
  if (t < 64) { sc1[t] = sc1g[t]; sh1[t] = sh1g[t]; }
  __syncthreads();
  const int rl = t >> 2, cq = t & 3;
  float ssum[8] = {}, ssq[8] = {};
  for (int tile = 0; tile < 8; ++tile) {
    const int rowbase = (blockIdx.x * 8 + tile) << 6;
    // ---- stage A = bf16(relu(bn1(act1))) ----
    {
      size_t r = (size_t)rowbase + rl;
      const uint4* pr = (const uint4*)(act1 + r * 64 + cq * 16);
      uint4 aa = pr[0], bb = pr[1];
      unsigned int uu[8] = {aa.x, aa.y, aa.z, aa.w, bb.x, bb.y, bb.z, bb.w};
      unsigned int pk[8];
#pragma unroll
      for (int q = 0; q < 8; ++q) {
        int c = cq * 16 + 2 * q;
        float v0 = bf2f((unsigned short)(uu[q] & 0xffffu));
        float v1 = bf2f((unsigned short)(uu[q] >> 16));
        float r0 = fmaxf(0.f, fmaf(v0, sc1[c], sh1[c]));
        float r1 = fmaxf(0.f, fmaf(v1, sc1[c + 1], sh1[c + 1]));
        pk[q] = (unsigned)f2bf(r0) | ((unsigned)f2bf(r1) << 16);
      }
      uint4* dst = (uint4*)&A[rl * 72 + cq * 16];
      dst[0] = make_uint4(pk[0], pk[1], pk[2], pk[3]);
      dst[1] = make_uint4(pk[4], pk[5], pk[6], pk[7]);
    }
    __syncthreads();  // S1: A visible
    // ---- MFMA ----
    const unsigned short* Arow = &A[(w * 16 + l15) * 72 + quad * 8];
    bf16x8 a0 = *(const bf16x8*)(Arow);
    bf16x8 a1 = *(const bf16x8*)(Arow + 32);
    f32x4 acc[8];
#pragma unroll
    for (int nt = 0; nt < 8; ++nt) {
      const unsigned short* Brow = &W2T[(nt * 16 + l15) * 72 + quad * 8];
      bf16x8 b0 = *(const bf16x8*)(Brow);
      bf16x8 b1 = *(const bf16x8*)(Brow + 32);
      f32x4 c0 = {0.f, 0.f, 0.f, 0.f};
      c0 = __builtin_amdgcn_mfma_f32_16x16x32_bf16(a0, b0, c0, 0, 0, 0);
      c0 = __builtin_amdgcn_mfma_f32_16x16x32_bf16(a1, b1, c0, 0, 0, 0);
      acc[nt] = c0;
    }
    // ---- stats + max/min extraction (col o = nt*16+l15, rows quad*4+reg) ----
#pragma unroll
    for (int nt = 0; nt < 8; ++nt) {
      float y0 = acc[nt][0], y1 = acc[nt][1], y2 = acc[nt][2], y3 = acc[nt][3];
      ssum[nt] += ((y0 + y1) + (y2 + y3));
      ssq[nt] = fmaf(y0, y0, ssq[nt]);
      ssq[nt] = fmaf(y1, y1, ssq[nt]);
      ssq[nt] = fmaf(y2, y2, ssq[nt]);
      ssq[nt] = fmaf(y3, y3, ssq[nt]);
      float mx = fmaxf(fmaxf(y0, y1), fmaxf(y2, y3));
      float mn = fminf(fminf(y0, y1), fminf(y2, y3));
      mx = fmaxf(mx, __shfl_xor(mx, 16, 64));
      mx = fmaxf(mx, __shfl_xor(mx, 32, 64));
      mn = fminf(mn, __shfl_xor(mn, 16, 64));
      mn = fminf(mn, __shfl_xor(mn, 32, 64));
      if (quad == 0) {
        Mred[w][nt * 16 + l15] = mx;
        Nred[w][nt * 16 + l15] = mn;
      }
    }
    __syncthreads();  // S2: Mred/Nred visible
    {
      int o = t & 127, g = t >> 7;  // waves (0,1)->group0, (2,3)->group1
      float mx = fmaxf(Mred[2 * g][o], Mred[2 * g + 1][o]);
      float mn = fminf(Nred[2 * g][o], Nred[2 * g + 1][o]);
      int bb2 = rowbase >> 15;
      int ss2 = ((rowbase >> 5) & 1023) + g;
      size_t oidx = ((size_t)bb2 * 128 + o) * 1024 + ss2;
      gmx[oidx] = mx;
      gmn[oidx] = mn;
    }
    __syncthreads();  // S3: Mred reads done; A reusable next tile
  }
  // ---- final stats reduce ----
#pragma unroll
  for (int nt = 0; nt < 8; ++nt) {
    float s1 = ssum[nt];
    s1 += __shfl_xor(s1, 16, 64);
    s1 += __shfl_xor(s1, 32, 64);
    float s2 = ssq[nt];
    s2 += __shfl_xor(s2, 16, 64);
    s2 += __shfl_xor(s2, 32, 64);
    if (quad == 0) {
      S1r[w][nt * 16 + l15] = s1;
      S2r[w][nt * 16 + l15] = s2;
    }
  }
  __syncthreads();
  if (t < 128) {
    int o = t;
    float s1 = S1r[0][o] + S1r[1][o] + S1r[2][o] + S1r[3][o];
    float s2 = S2r[0][o] + S2r[1][o] + S2r[2][o] + S2r[3][o];
    partials2[(size_t)o * 1024 + blockIdx.x] = s1;
    partials2[(size_t)(128 + o) * 1024 + blockIdx.x] = s2;
  }
}

// ---------------------------------------------------------------------------
// P4f: feats[b][o][s] = relu(sc2[o] * (sc2>=0 ? gmx : gmn) + sh2[o]).
// ---------------------------------------------------------------------------
__global__ __launch_bounds__(256) void p4f_kernel(
    const float* __restrict__ gmx, const float* __restrict__ gmn,
    const float* __restrict__ sc2g, const float* __restrict__ sh2g,
    float* __restrict__ feats) {
  const int bo = blockIdx.x >> 2;
  const int s = ((blockIdx.x & 3) << 8) + threadIdx.x;
  const int o = bo & 127;
  const float sc = sc2g[o], sh = sh2g[o];
  size_t idx = (size_t)bo * 1024 + s;
  float v = (sc >= 0.f) ? gmx[idx] : gmn[idx];
  feats[idx] = fmaxf(0.f, fmaf(v, sc, sh));
}

// ---------------------------------------------------------------------------
extern "C" void kernel_launch(void* const* d_in, const int* in_sizes, int n_in,
                              void* d_out, int out_size, void* d_ws, size_t ws_size,
                              hipStream_t stream) {
  const float* xyz = (const float*)d_in[0];
  const float* points = (const float*)d_in[1];
  const float* w0 = (const float*)d_in[2];
  const float* g0 = (const float*)d_in[3];
  const float* b0 = (const float*)d_in[4];
  const float* w1 = (const float*)d_in[5];
  const float* g1 = (const float*)d_in[6];
  const float* b1 = (const float*)d_in[7];
  const float* w2 = (const float*)d_in[8];
  const float* g2 = (const float*)d_in[9];
  const float* b2 = (const float*)d_in[10];

  float* out = (float*)d_out;
  float* newxyz = out;            // (16,1024,3)
  float* feats = out + 49152;     // (16,128,1024)

  char* ws = (char*)d_ws;
  float* P0 = (float*)ws;                                        // 16 MB  [b][n][64]
  // gmx/gmn reuse the P0 region: P0's last consumer is p2; p3 writes these.
  float* gmx = (float*)ws;                                       // 8 MB [b][o][s]
  float* gmn = (float*)(ws + (size_t)(8u << 20));                // 8 MB
  int* gidx = (int*)(ws + (size_t)(16u << 20));                  // 2 MB
  unsigned short* act1 = (unsigned short*)(ws + (size_t)(18u << 20));  // 64 MB bf16
  float* partials0 = (float*)(ws + (size_t)(82u << 20));         // 2 MB   [128][4096]
  float* partials1 = (float*)(ws + (size_t)(84u << 20));         // 0.5 MB [128][1024]
  float* partials2 = (float*)(ws + (size_t)(85u << 20));         // 1 MB   [256][1024]
  float* sc0 = (float*)(ws + (size_t)(86u << 20));               // 6*128 floats
  float* sh0 = sc0 + 128;
  float* sc1 = sc0 + 256;
  float* sh1 = sc0 + 384;
  float* sc2 = sc0 + 512;
  float* sh2 = sc0 + 640;

  fps_kernel<<<16, 256, 0, stream>>>(xyz, newxyz);
  p0_kernel<<<1024, 256, 0, stream>>>(points, w0, P0);
  ballquery_stats0_kernel<<<4096, 256, 0, stream>>>(xyz, newxyz, P0, w0, gidx, partials0);
  finalize_kernel<<<64, 256, 0, stream>>>(partials0, 64, 4096, g0, b0, sc0, sh0);
  p2_kernel<<<1024, 256, 0, stream>>>(xyz, newxyz, P0, gidx, w0, w1, sc0, sh0, act1, partials1);
  finalize_kernel<<<64, 256, 0, stream>>>(partials1, 64, 1024, g1, b1, sc1, sh1);
  p3_kernel<<<1024, 256, 0, stream>>>(act1, w2, sc1, sh1, partials2, gmx, gmn);
  finalize_kernel<<<128, 256, 0, stream>>>(partials2, 128, 1024, g2, b2, sc2, sh2);
  p4f_kernel<<<8192, 256, 0, stream>>>(gmx, gmn, sc2, sh2, feats);
}